// Round 8
// baseline (3499.208 us; speedup 1.0000x reference)
//
#include <hip/hip_runtime.h>
#include <hip/hip_bf16.h>

namespace {
constexpr int B = 8;
constexpr int N = 4096;
constexpr int KNN = 20;
constexpr int NSEG = 4;
constexpr int SEGLEN = N / NSEG;   // 1024
constexpr int CAP = 24;
constexpr int SLOTS = NSEG * CAP;  // 96

// workspace layout (bytes)
constexpr size_t OFF_IDX  = 0;                          // int [B][N][KNN]
constexpr size_t SZ_IDX   = (size_t)B * N * KNN * 4;
constexpr size_t OFF_T    = OFF_IDX + SZ_IDX;           // knn scratch region
constexpr size_t SZ_T     = (size_t)B * N * 128 * 4;
constexpr size_t OFF_CAT  = OFF_T + SZ_T;               // float [B][N][320]
constexpr size_t SZ_CAT   = (size_t)B * N * 320 * 4;
constexpr size_t OFF_PV   = OFF_CAT + SZ_CAT;           // float [B][1024][32]
constexpr size_t SZ_PV    = (size_t)B * 1024 * 32 * 4;
constexpr size_t OFF_PI   = OFF_PV + SZ_PV;             // int   [B][1024][32]
constexpr size_t OFF_GLOB = OFF_PI + SZ_PV;             // float [B][1024]
constexpr size_t OFF_H    = OFF_GLOB + (size_t)B * 1024 * 4;  // float [B][512]
// knn scratch overlaid on T + head of CAT (dead once merge completes):
constexpr size_t OFF_LD   = OFF_T;                      // float [B*N][SLOTS]
constexpr size_t SZ_LD    = (size_t)B * N * SLOTS * 4;
constexpr size_t OFF_LJ   = OFF_LD + SZ_LD;             // int   [B*N][SLOTS]
constexpr size_t OFF_CNT  = OFF_LJ + SZ_LD;             // int   [B*N][NSEG]
}  // namespace

typedef float v2f __attribute__((ext_vector_type(2)));

// Non-contractable fp32 ops: bit-exact match to np's mul-then-add serial loops.
__device__ __forceinline__ float mulrn(float a, float b) {
#pragma clang fp contract(off)
  return a * b;
}
__device__ __forceinline__ float addrn(float a, float b) {
#pragma clang fp contract(off)
  return a + b;
}
__device__ __forceinline__ float subrn(float a, float b) {
#pragma clang fp contract(off)
  return a - b;
}
// Packed (v_pk_mul_f32 / v_pk_add_f32): per-element IEEE rn == scalar ops.
__device__ __forceinline__ v2f mulrn2(v2f a, v2f b) {
#pragma clang fp contract(off)
  return a * b;
}
__device__ __forceinline__ v2f addrn2(v2f a, v2f b) {
#pragma clang fp contract(off)
  return a + b;
}

// ---------------------------------------------------------------------------
// kNN: per-thread scan of one row-segment keeping sorted top-20 distances,
// then recovery pass collects (d, j) with d <= theta in ascending-j order.
// ---------------------------------------------------------------------------
__global__ __launch_bounds__(256) void knn_scan(
    const float* __restrict__ pts,
    float* __restrict__ listd, int* __restrict__ listj, int* __restrict__ counts) {
  __shared__ float4 sp[N];  // 64 KB: (x, y, z, sq)
  const int b = blockIdx.y;
  const int tid = threadIdx.x;
  const float* px = pts + (size_t)b * 3 * N;
  for (int i = tid; i < N; i += 256) {
    const float x = px[i];
    const float y = px[N + i];
    const float z = px[2 * N + i];
    const float sq = addrn(addrn(mulrn(x, x), mulrn(y, y)), mulrn(z, z));
    sp[i] = make_float4(x, y, z, sq);
  }
  __syncthreads();
  const int row = blockIdx.x * 64 + (tid & 63);
  const int seg = tid >> 6;
  const float4 q = sp[row];
  float ds[KNN];
#pragma unroll
  for (int t = 0; t < KNN; ++t) ds[t] = 3.0e38f;
  const int j0 = seg * SEGLEN;
#pragma unroll 2
  for (int jj = 0; jj < SEGLEN; jj += 2) {
    const float4 c0 = sp[j0 + jj];
    const float4 c1 = sp[j0 + jj + 1];
    v2f t0 = mulrn2((v2f){q.x, q.x}, (v2f){c0.x, c1.x});
    t0 = addrn2(t0, mulrn2((v2f){q.y, q.y}, (v2f){c0.y, c1.y}));
    t0 = addrn2(t0, mulrn2((v2f){q.z, q.z}, (v2f){c0.z, c1.z}));
    v2f d2 = addrn2((v2f){q.w, q.w}, (v2f){c0.w, c1.w});
    d2 = d2 - mulrn2((v2f){2.0f, 2.0f}, t0);
#pragma unroll
    for (int u = 0; u < 2; ++u) {
      const float d = u ? d2.y : d2.x;
      if (d < ds[KNN - 1]) {
        float cur = d;
#pragma unroll
        for (int t = 0; t < KNN; ++t) {
          const float lo = fminf(cur, ds[t]);
          cur = fmaxf(cur, ds[t]);
          ds[t] = lo;
        }
      }
    }
  }
  const float th = ds[KNN - 1];
  const int rbase = (b * N + row) * NSEG + seg;
  float* ld = listd + (size_t)(b * N + row) * SLOTS + seg * CAP;
  int* lj = listj + (size_t)(b * N + row) * SLOTS + seg * CAP;
  int cnt = 0;
#pragma unroll 2
  for (int jj = 0; jj < SEGLEN; jj += 2) {
    const float4 c0 = sp[j0 + jj];
    const float4 c1 = sp[j0 + jj + 1];
    v2f t0 = mulrn2((v2f){q.x, q.x}, (v2f){c0.x, c1.x});
    t0 = addrn2(t0, mulrn2((v2f){q.y, q.y}, (v2f){c0.y, c1.y}));
    t0 = addrn2(t0, mulrn2((v2f){q.z, q.z}, (v2f){c0.z, c1.z}));
    v2f d2 = addrn2((v2f){q.w, q.w}, (v2f){c0.w, c1.w});
    d2 = d2 - mulrn2((v2f){2.0f, 2.0f}, t0);
#pragma unroll
    for (int u = 0; u < 2; ++u) {
      const float d = u ? d2.y : d2.x;
      if (d <= th && cnt < CAP) {
        ld[cnt] = d;
        lj[cnt] = j0 + jj + u;
        ++cnt;
      }
    }
  }
  counts[rbase] = cnt;
}

// Merge: per row, select 20 lexicographically-smallest (dist, j) from <=96
// candidates via monotone uint64 keys.
__global__ __launch_bounds__(64) void knn_merge(
    const float* __restrict__ listd, const int* __restrict__ listj,
    const int* __restrict__ counts, int* __restrict__ idxout) {
  __shared__ unsigned long long keys[64][SLOTS + 1];  // 49,664 B
  const int r0 = blockIdx.x * 64;
  const int t = threadIdx.x;
  for (int i = t; i < 64 * SLOTS; i += 64) {
    const int rr = i / SLOTS;
    const int sl = i % SLOTS;
    const int seg = sl / CAP;
    const int e = sl % CAP;
    const int row = r0 + rr;
    unsigned long long key = 0xFFFFFFFE00000000ULL | (unsigned)row;  // fallback: self
    if (e < counts[row * NSEG + seg]) {
      const float d = listd[(size_t)row * SLOTS + sl];
      unsigned ub = __float_as_uint(d);
      ub ^= (ub & 0x80000000u) ? 0xFFFFFFFFu : 0x80000000u;
      key = ((unsigned long long)ub << 32) | (unsigned)listj[(size_t)row * SLOTS + sl];
    }
    keys[rr][sl] = key;
  }
  __syncthreads();
  int* outp = idxout + (size_t)(r0 + t) * KNN;
  for (int sel = 0; sel < KNN; ++sel) {
    unsigned long long best = ~0ULL;
    int bs = 0;
#pragma unroll 8
    for (int sl = 0; sl < SLOTS; ++sl) {
      const unsigned long long k2 = keys[t][sl];
      if (k2 < best) { best = k2; bs = sl; }
    }
    keys[t][bs] = ~0ULL;
    outp[sel] = (int)(best & 0xFFFFFFFFu);
  }
}

// ---------------------------------------------------------------------------
// EdgeConv, BIT-EXACT serial semantics per (o, n, k):
//   y = sum_c W[o,c]*ctr[c]  (prefix P)  then  += W[o,64+c]*(nb[c]-ctr[c]).
// ---------------------------------------------------------------------------

// Layer 1 (cin=3): wave per point, lane = output o.
__global__ __launch_bounds__(256) void ec_layer1(
    const float* __restrict__ pts, const int* __restrict__ idx,
    const float* __restrict__ w, const float* __restrict__ s,
    const float* __restrict__ bi, float* __restrict__ cat) {
  const int b = blockIdx.y;
  const int n = blockIdx.x * 4 + (threadIdx.x >> 6);
  const int o = threadIdx.x & 63;
  const float* p = pts + (size_t)b * 3 * N;
  const float xix = p[n], xiy = p[N + n], xiz = p[2 * N + n];
  const float* wr = w + o * 6;
  const float w0 = wr[0], w1 = wr[1], w2 = wr[2], w3 = wr[3], w4 = wr[4], w5 = wr[5];
  float P = mulrn(w0, xix);
  P = addrn(P, mulrn(w1, xiy));
  P = addrn(P, mulrn(w2, xiz));
  const float so = s[o], bo = bi[o];
  const int* ip = idx + ((size_t)b * N + n) * KNN;
  float m = 0.0f;
#pragma unroll 4
  for (int k = 0; k < KNN; ++k) {
    int j = ip[k];
    if ((unsigned)j >= (unsigned)N) j = n;
    const float ex = subrn(p[j], xix);
    const float ey = subrn(p[N + j], xiy);
    const float ez = subrn(p[2 * N + j], xiz);
    float acc = addrn(P, mulrn(w3, ex));
    acc = addrn(acc, mulrn(w4, ey));
    acc = addrn(acc, mulrn(w5, ez));
    m = fmaxf(m, addrn(mulrn(so, acc), bo));
  }
  cat[((size_t)b * N + n) * 320 + o] = m;
}

// 64-in/64-out EdgeConv layer, PHASE-SPLIT:
//  A) stage W to LDS (33 KB), B) per-lane wreg + serial prefix P,
//  C) barrier, then e-vectors for all 10 neighbor-pairs gathered and written
//     to LDS (aliased over the W region — safe post-barrier), D) pure
//     read+MAC phase: 10 independent pk chains, no interleaved writes/waits.
__global__ __launch_bounds__(256, 4) void ec_layer64(
    const float* __restrict__ cat, int inoff, const int* __restrict__ idx,
    const float* __restrict__ w, const float* __restrict__ s,
    const float* __restrict__ bi, float* __restrict__ catout, int outoff) {
  __shared__ float wst[64 * 130];   // 33,280 B (aliased as est in phase C/D)
  __shared__ float xibuf[4][64];    // 1 KB
  for (int l = threadIdx.x; l < 64 * 128; l += 256) {
    wst[(l >> 7) * 130 + (l & 127)] = w[l];
  }
  __syncthreads();
  const int b = blockIdx.y;
  const int wv = threadIdx.x >> 6;
  const int n = blockIdx.x * 4 + wv;
  const int o = threadIdx.x & 63;
  // second-half weights -> registers
  float wreg[64];
#pragma unroll
  for (int c = 0; c < 64; ++c) wreg[c] = wst[o * 130 + 64 + c];
  const float xi = cat[((size_t)b * N + n) * 320 + inoff + o];
  xibuf[wv][o] = xi;
  // prefix P = serial sum_{c<64} W[o][c] * x_i[c]  (x_i broadcast from xibuf)
  float P;
  {
    const float4* x4 = (const float4*)&xibuf[wv][0];
    const float4 v0 = x4[0];
    P = mulrn(wst[o * 130 + 0], v0.x);
    P = addrn(P, mulrn(wst[o * 130 + 1], v0.y));
    P = addrn(P, mulrn(wst[o * 130 + 2], v0.z));
    P = addrn(P, mulrn(wst[o * 130 + 3], v0.w));
#pragma unroll
    for (int c4 = 1; c4 < 16; ++c4) {
      const float4 v = x4[c4];
      P = addrn(P, mulrn(wst[o * 130 + 4 * c4 + 0], v.x));
      P = addrn(P, mulrn(wst[o * 130 + 4 * c4 + 1], v.y));
      P = addrn(P, mulrn(wst[o * 130 + 4 * c4 + 2], v.z));
      P = addrn(P, mulrn(wst[o * 130 + 4 * c4 + 3], v.w));
    }
  }
  __syncthreads();  // all waves done with wst -> safe to alias as est
  // est[wv][kp][c]: v2f e-vector for pair kp; stride 66 v2f (528 B, 16B-aligned)
  v2f* est = (v2f*)wst;
  v2f* myest = est + (size_t)(wv * 10) * 66;
  const int* ip = idx + ((size_t)b * N + n) * KNN;
  const float* catb = cat + (size_t)b * N * 320 + inoff + o;
  // phase C: all 20 gathers in flight, 10 pair-packed LDS writes
#pragma unroll
  for (int kp = 0; kp < 10; ++kp) {
    int j0 = ip[2 * kp];
    int j1 = ip[2 * kp + 1];
    if ((unsigned)j0 >= (unsigned)N) j0 = n;
    if ((unsigned)j1 >= (unsigned)N) j1 = n;
    const float xj0 = catb[(size_t)j0 * 320];
    const float xj1 = catb[(size_t)j1 * 320];
    myest[kp * 66 + o] = (v2f){subrn(xj0, xi), subrn(xj1, xi)};
  }
  // phase D: 10 independent serial-c chains (same-wave LDS, lgkmcnt-ordered)
  const float so = s[o], bo = bi[o];
  float m = 0.0f;
#pragma unroll 2
  for (int kp = 0; kp < 10; ++kp) {
    const float4* e4 = (const float4*)(myest + kp * 66);  // 2 v2f per read
    v2f acc = (v2f){P, P};
#pragma unroll
    for (int r = 0; r < 32; ++r) {
      const float4 q = e4[r];  // broadcast: e[2r] = (q.x,q.y), e[2r+1] = (q.z,q.w)
      acc = addrn2(acc, mulrn2((v2f){wreg[2 * r], wreg[2 * r]}, (v2f){q.x, q.y}));
      acc = addrn2(acc, mulrn2((v2f){wreg[2 * r + 1], wreg[2 * r + 1]}, (v2f){q.z, q.w}));
    }
    const v2f vv = addrn2(mulrn2((v2f){so, so}, acc), (v2f){bo, bo});
    m = fmaxf(m, fmaxf(vv.x, vv.y));
  }
  catout[((size_t)b * N + n) * 320 + outoff + o] = m;
}

// ---------------------------------------------------------------------------
// Local layer: loc[o][n] = relu(s*<W[o,:],cat[n,:]>+b), serial ascending c,
// output-pair pk-packed, b128 LDS fragments (4-consecutive mapping):
//   points  = 64e' + 4g + pi  (e'∈{0,1}, pi∈0..3)
//   outputs = 64f' + 4h + c   (f'∈{0,1}, c∈0..3)
// Register-prefetch double-buffered staging.
// ---------------------------------------------------------------------------
__global__ __launch_bounds__(256) void local_gemm(
    const float* __restrict__ cat, const float* __restrict__ w,
    const float* __restrict__ s, const float* __restrict__ bi,
    float* __restrict__ pval, int* __restrict__ pidx) {
  constexpr int KC = 32;
  constexpr int XS = 132;  // 16B-aligned rows; b128 frag reads conflict-free
  __shared__ float smem[KC * XS * 2];  // 33,792 B
  float* xs = smem;
  float* wsd = smem + KC * XS;
  const int t = threadIdx.x;
  const int q0 = blockIdx.x * 128;
  const int ptile = blockIdx.y;
  const size_t pt0 = (size_t)ptile * 128;
  const int g = t & 15;   // point frag base 4g
  const int h = t >> 4;   // output frag base 4h
  v2f acc2[2][2][4][2];   // [e'][f'][pi][u] -> outputs 64f'+4h+2u(+1)
#pragma unroll
  for (int ep = 0; ep < 2; ++ep)
#pragma unroll
    for (int fp = 0; fp < 2; ++fp)
#pragma unroll
      for (int pi = 0; pi < 4; ++pi)
#pragma unroll
        for (int u = 0; u < 2; ++u) acc2[ep][fp][pi][u] = (v2f){0.f, 0.f};

  const int lk = t & 31;
  const int lp = t >> 5;
  const float* catp = cat + pt0 * 320 + lk;
  const float* wp = w + (size_t)q0 * 320 + lk;
  float rx[16], rw[16];
#pragma unroll
  for (int i = 0; i < 16; ++i) rx[i] = catp[(size_t)(lp + 8 * i) * 320];
#pragma unroll
  for (int i = 0; i < 16; ++i) rw[i] = wp[(size_t)(lp + 8 * i) * 320];

  for (int kc = 0; kc < 320; kc += KC) {
#pragma unroll
    for (int i = 0; i < 16; ++i) xs[lk * XS + lp + 8 * i] = rx[i];
#pragma unroll
    for (int i = 0; i < 16; ++i) wsd[lk * XS + lp + 8 * i] = rw[i];
    __syncthreads();
    if (kc + KC < 320) {  // prefetch next chunk into registers
      const int ko = kc + KC;
#pragma unroll
      for (int i = 0; i < 16; ++i) rx[i] = catp[(size_t)(lp + 8 * i) * 320 + ko];
#pragma unroll
      for (int i = 0; i < 16; ++i) rw[i] = wp[(size_t)(lp + 8 * i) * 320 + ko];
    }
#pragma unroll
    for (int k = 0; k < KC; ++k) {
      float4 xf[2], wf[2];
#pragma unroll
      for (int ep = 0; ep < 2; ++ep)
        xf[ep] = *(const float4*)&xs[k * XS + 64 * ep + 4 * g];
#pragma unroll
      for (int fp = 0; fp < 2; ++fp)
        wf[fp] = *(const float4*)&wsd[k * XS + 64 * fp + 4 * h];
#pragma unroll
      for (int ep = 0; ep < 2; ++ep) {
        const float xv[4] = {xf[ep].x, xf[ep].y, xf[ep].z, xf[ep].w};
#pragma unroll
        for (int fp = 0; fp < 2; ++fp) {
          const v2f w0 = (v2f){wf[fp].x, wf[fp].y};
          const v2f w1 = (v2f){wf[fp].z, wf[fp].w};
#pragma unroll
          for (int pi = 0; pi < 4; ++pi) {
            const v2f xx = (v2f){xv[pi], xv[pi]};
            acc2[ep][fp][pi][0] = addrn2(acc2[ep][fp][pi][0], mulrn2(w0, xx));
            acc2[ep][fp][pi][1] = addrn2(acc2[ep][fp][pi][1], mulrn2(w1, xx));
          }
        }
      }
    }
    __syncthreads();
  }
  // epilogue: relu(s*acc+b), per-thread argmax over 8 points in ascending
  // point order (e' major, pi minor -> ascending) = first occurrence.
  const int bb = ptile >> 5;
  const int blk = ptile & 31;
  float mv[8];
  int mi[8];
#pragma unroll
  for (int fp = 0; fp < 2; ++fp)
#pragma unroll
    for (int c = 0; c < 4; ++c) {
      const int f = fp * 4 + c;         // local slot
      const int cl = 64 * fp + 4 * h + c;  // output index
      const float sc = s[q0 + cl];
      const float bc = bi[q0 + cl];
      mv[f] = -1.f;
      mi[f] = 0;
#pragma unroll
      for (int ep = 0; ep < 2; ++ep)
#pragma unroll
        for (int pi = 0; pi < 4; ++pi) {
          const v2f a2 = acc2[ep][fp][pi][c >> 1];
          const float a = (c & 1) ? a2.y : a2.x;
          const float v = fmaxf(addrn(mulrn(sc, a), bc), 0.f);
          if (v > mv[f]) { mv[f] = v; mi[f] = 64 * ep + 4 * g + pi; }
        }
    }
  __syncthreads();
  float* smv = smem;
  int* smi = (int*)(smem + 16 * 132);
#pragma unroll
  for (int fp = 0; fp < 2; ++fp)
#pragma unroll
    for (int c = 0; c < 4; ++c) {
      const int cl = 64 * fp + 4 * h + c;
      smv[g * 132 + cl] = mv[fp * 4 + c];
      smi[g * 132 + cl] = mi[fp * 4 + c];
    }
  __syncthreads();
  if (t < 128) {
    float best = smv[t];
    int bidx = smi[t];
    for (int gg = 1; gg < 16; ++gg) {
      const float v = smv[gg * 132 + t];
      const int vi = smi[gg * 132 + t];
      // candidates g-interleaved: ties resolve to SMALLEST point idx
      if (v > best || (v == best && vi < bidx)) { best = v; bidx = vi; }
    }
    const int n_l = blk * 128 + bidx;
    const size_t po = ((size_t)bb * 1024 + q0 + t) * 32 + blk;
    pval[po] = best;
    pidx[po] = n_l;
  }
}

__global__ __launch_bounds__(256) void final_reduce(
    const float* __restrict__ pval, const int* __restrict__ pidx,
    float* __restrict__ glob, float* __restrict__ oidx) {
  const int o = blockIdx.x * 256 + threadIdx.x;  // 8192 = B*1024
  const float* pv = pval + (size_t)o * 32;
  const int* pi = pidx + (size_t)o * 32;
  float best = pv[0];
  int bi = pi[0];
  for (int k = 1; k < 32; ++k) {
    const float v = pv[k];
    // tiles are ascending disjoint point ranges: strict > = first occurrence
    if (v > best) { best = v; bi = pi[k]; }
  }
  glob[o] = best;
  oidx[o] = (float)bi;
}

template <int KIN, int OUTS>
__global__ __launch_bounds__(256) void dense_wave(
    const float* __restrict__ in, const float* __restrict__ w,
    const float* __restrict__ s, const float* __restrict__ bi,
    float* __restrict__ out) {
  const int wid = (blockIdx.x * 256 + threadIdx.x) >> 6;
  const int lane = threadIdx.x & 63;
  const int b = wid / OUTS;
  const int o = wid % OUTS;
  const float* ip = in + (size_t)b * KIN;
  const float* wr = w + (size_t)o * KIN;
  float acc = 0.f;
  for (int k = lane; k < KIN; k += 64) acc = fmaf(wr[k], ip[k], acc);
#pragma unroll
  for (int off = 32; off; off >>= 1) acc += __shfl_down(acc, off);
  if (lane == 0) out[(size_t)b * OUTS + o] = fmaxf(fmaf(s[o], acc, bi[o]), 0.f);
}

extern "C" void kernel_launch(void* const* d_in, const int* in_sizes, int n_in,
                              void* d_out, int out_size, void* d_ws, size_t ws_size,
                              hipStream_t stream) {
  (void)in_sizes; (void)n_in; (void)out_size; (void)ws_size;
  const float* pts = (const float*)d_in[0];
  const float* ec_w[4] = {(const float*)d_in[1], (const float*)d_in[4],
                          (const float*)d_in[7], (const float*)d_in[10]};
  const float* ec_s[4] = {(const float*)d_in[2], (const float*)d_in[5],
                          (const float*)d_in[8], (const float*)d_in[11]};
  const float* ec_b[4] = {(const float*)d_in[3], (const float*)d_in[6],
                          (const float*)d_in[9], (const float*)d_in[12]};
  const float* local_w = (const float*)d_in[13];
  const float* local_s = (const float*)d_in[14];
  const float* local_b = (const float*)d_in[15];
  const float* g_w0 = (const float*)d_in[16];
  const float* g_s0 = (const float*)d_in[17];
  const float* g_b0 = (const float*)d_in[18];
  const float* g_w1 = (const float*)d_in[19];
  const float* g_s1 = (const float*)d_in[20];
  const float* g_b1 = (const float*)d_in[21];

  char* ws = (char*)d_ws;
  int* idxbuf = (int*)(ws + OFF_IDX);
  float* cat = (float*)(ws + OFF_CAT);
  float* pv = (float*)(ws + OFF_PV);
  int* pi = (int*)(ws + OFF_PI);
  float* glob = (float*)(ws + OFF_GLOB);
  float* hbuf = (float*)(ws + OFF_H);
  float* listd = (float*)(ws + OFF_LD);
  int* listj = (int*)(ws + OFF_LJ);
  int* counts = (int*)(ws + OFF_CNT);
  float* outv = (float*)d_out;   // [8][256]  fp32
  float* oidx = outv + 2048;     // [8][1024] fp32 (indices as floats)

  knn_scan<<<dim3(64, 8), 256, 0, stream>>>(pts, listd, listj, counts);
  knn_merge<<<dim3(512), 64, 0, stream>>>(listd, listj, counts, idxbuf);

  // layer 1 (3 -> 64)
  ec_layer1<<<dim3(1024, 8), 256, 0, stream>>>(pts, idxbuf, ec_w[0], ec_s[0], ec_b[0], cat);
  // layer 2 (64 -> 64)
  ec_layer64<<<dim3(1024, 8), 256, 0, stream>>>(cat, 0, idxbuf, ec_w[1], ec_s[1], ec_b[1], cat, 64);
  // layer 3 (64 -> 64)
  ec_layer64<<<dim3(1024, 8), 256, 0, stream>>>(cat, 64, idxbuf, ec_w[2], ec_s[2], ec_b[2], cat, 128);
  // layer 4 (64 -> 128), two 64-output halves (outputs independent -> exact)
  ec_layer64<<<dim3(1024, 8), 256, 0, stream>>>(cat, 128, idxbuf, ec_w[3], ec_s[3], ec_b[3], cat, 192);
  ec_layer64<<<dim3(1024, 8), 256, 0, stream>>>(cat, 128, idxbuf, ec_w[3] + 64 * 128,
                                                ec_s[3] + 64, ec_b[3] + 64, cat, 256);

  local_gemm<<<dim3(8, 256), 256, 0, stream>>>(cat, local_w, local_s, local_b, pv, pi);
  final_reduce<<<dim3(32), 256, 0, stream>>>(pv, pi, glob, oidx);
  dense_wave<1024, 512><<<dim3(1024), 256, 0, stream>>>(glob, g_w0, g_s0, g_b0, hbuf);
  dense_wave<512, 256><<<dim3(512), 256, 0, stream>>>(hbuf, g_w1, g_s1, g_b1, outv);
}

// Round 9
// 2041.482 us; speedup vs baseline: 1.7141x; 1.7141x over previous
//
#include <hip/hip_runtime.h>
#include <hip/hip_bf16.h>

namespace {
constexpr int B = 8;
constexpr int N = 4096;
constexpr int KNN = 20;
constexpr int NSEG = 4;
constexpr int SEGLEN = N / NSEG;   // 1024
constexpr int CAP = 24;
constexpr int SLOTS = NSEG * CAP;  // 96

// workspace layout (bytes)
constexpr size_t OFF_IDX  = 0;                          // int [B][N][KNN]
constexpr size_t SZ_IDX   = (size_t)B * N * KNN * 4;
constexpr size_t OFF_T    = OFF_IDX + SZ_IDX;           // knn scratch region
constexpr size_t SZ_T     = (size_t)B * N * 128 * 4;
constexpr size_t OFF_CAT  = OFF_T + SZ_T;               // float [B][N][320]
constexpr size_t SZ_CAT   = (size_t)B * N * 320 * 4;
constexpr size_t OFF_PV   = OFF_CAT + SZ_CAT;           // float [B][1024][32]
constexpr size_t SZ_PV    = (size_t)B * 1024 * 32 * 4;
constexpr size_t OFF_PI   = OFF_PV + SZ_PV;             // int   [B][1024][32]
constexpr size_t OFF_GLOB = OFF_PI + SZ_PV;             // float [B][1024]
constexpr size_t OFF_H    = OFF_GLOB + (size_t)B * 1024 * 4;  // float [B][512]
// knn scratch overlaid on T + head of CAT (dead once merge completes):
constexpr size_t OFF_LD   = OFF_T;                      // float [B*N][SLOTS]
constexpr size_t SZ_LD    = (size_t)B * N * SLOTS * 4;
constexpr size_t OFF_LJ   = OFF_LD + SZ_LD;             // int   [B*N][SLOTS]
constexpr size_t OFF_CNT  = OFF_LJ + SZ_LD;             // int   [B*N][NSEG]
}  // namespace

typedef float v2f __attribute__((ext_vector_type(2)));

// Non-contractable fp32 ops: bit-exact match to np's mul-then-add serial loops.
__device__ __forceinline__ float mulrn(float a, float b) {
#pragma clang fp contract(off)
  return a * b;
}
__device__ __forceinline__ float addrn(float a, float b) {
#pragma clang fp contract(off)
  return a + b;
}
__device__ __forceinline__ float subrn(float a, float b) {
#pragma clang fp contract(off)
  return a - b;
}
// Packed (v_pk_mul_f32 / v_pk_add_f32): per-element IEEE rn == scalar ops.
__device__ __forceinline__ v2f mulrn2(v2f a, v2f b) {
#pragma clang fp contract(off)
  return a * b;
}
__device__ __forceinline__ v2f addrn2(v2f a, v2f b) {
#pragma clang fp contract(off)
  return a + b;
}

// ---------------------------------------------------------------------------
// kNN: per-thread scan of one row-segment keeping sorted top-20 distances,
// then recovery pass collects (d, j) with d <= theta in ascending-j order.
// ---------------------------------------------------------------------------
__global__ __launch_bounds__(256) void knn_scan(
    const float* __restrict__ pts,
    float* __restrict__ listd, int* __restrict__ listj, int* __restrict__ counts) {
  __shared__ float4 sp[N];  // 64 KB: (x, y, z, sq)
  const int b = blockIdx.y;
  const int tid = threadIdx.x;
  const float* px = pts + (size_t)b * 3 * N;
  for (int i = tid; i < N; i += 256) {
    const float x = px[i];
    const float y = px[N + i];
    const float z = px[2 * N + i];
    const float sq = addrn(addrn(mulrn(x, x), mulrn(y, y)), mulrn(z, z));
    sp[i] = make_float4(x, y, z, sq);
  }
  __syncthreads();
  const int row = blockIdx.x * 64 + (tid & 63);
  const int seg = tid >> 6;
  const float4 q = sp[row];
  float ds[KNN];
#pragma unroll
  for (int t = 0; t < KNN; ++t) ds[t] = 3.0e38f;
  const int j0 = seg * SEGLEN;
#pragma unroll 2
  for (int jj = 0; jj < SEGLEN; jj += 2) {
    const float4 c0 = sp[j0 + jj];
    const float4 c1 = sp[j0 + jj + 1];
    v2f t0 = mulrn2((v2f){q.x, q.x}, (v2f){c0.x, c1.x});
    t0 = addrn2(t0, mulrn2((v2f){q.y, q.y}, (v2f){c0.y, c1.y}));
    t0 = addrn2(t0, mulrn2((v2f){q.z, q.z}, (v2f){c0.z, c1.z}));
    v2f d2 = addrn2((v2f){q.w, q.w}, (v2f){c0.w, c1.w});
    d2 = d2 - mulrn2((v2f){2.0f, 2.0f}, t0);
#pragma unroll
    for (int u = 0; u < 2; ++u) {
      const float d = u ? d2.y : d2.x;
      if (d < ds[KNN - 1]) {
        float cur = d;
#pragma unroll
        for (int t = 0; t < KNN; ++t) {
          const float lo = fminf(cur, ds[t]);
          cur = fmaxf(cur, ds[t]);
          ds[t] = lo;
        }
      }
    }
  }
  const float th = ds[KNN - 1];
  const int rbase = (b * N + row) * NSEG + seg;
  float* ld = listd + (size_t)(b * N + row) * SLOTS + seg * CAP;
  int* lj = listj + (size_t)(b * N + row) * SLOTS + seg * CAP;
  int cnt = 0;
#pragma unroll 2
  for (int jj = 0; jj < SEGLEN; jj += 2) {
    const float4 c0 = sp[j0 + jj];
    const float4 c1 = sp[j0 + jj + 1];
    v2f t0 = mulrn2((v2f){q.x, q.x}, (v2f){c0.x, c1.x});
    t0 = addrn2(t0, mulrn2((v2f){q.y, q.y}, (v2f){c0.y, c1.y}));
    t0 = addrn2(t0, mulrn2((v2f){q.z, q.z}, (v2f){c0.z, c1.z}));
    v2f d2 = addrn2((v2f){q.w, q.w}, (v2f){c0.w, c1.w});
    d2 = d2 - mulrn2((v2f){2.0f, 2.0f}, t0);
#pragma unroll
    for (int u = 0; u < 2; ++u) {
      const float d = u ? d2.y : d2.x;
      if (d <= th && cnt < CAP) {
        ld[cnt] = d;
        lj[cnt] = j0 + jj + u;
        ++cnt;
      }
    }
  }
  counts[rbase] = cnt;
}

// Merge: per row, select 20 lexicographically-smallest (dist, j) from <=96
// candidates via monotone uint64 keys.
__global__ __launch_bounds__(64) void knn_merge(
    const float* __restrict__ listd, const int* __restrict__ listj,
    const int* __restrict__ counts, int* __restrict__ idxout) {
  __shared__ unsigned long long keys[64][SLOTS + 1];  // 49,664 B
  const int r0 = blockIdx.x * 64;
  const int t = threadIdx.x;
  for (int i = t; i < 64 * SLOTS; i += 64) {
    const int rr = i / SLOTS;
    const int sl = i % SLOTS;
    const int seg = sl / CAP;
    const int e = sl % CAP;
    const int row = r0 + rr;
    unsigned long long key = 0xFFFFFFFE00000000ULL | (unsigned)row;  // fallback: self
    if (e < counts[row * NSEG + seg]) {
      const float d = listd[(size_t)row * SLOTS + sl];
      unsigned ub = __float_as_uint(d);
      ub ^= (ub & 0x80000000u) ? 0xFFFFFFFFu : 0x80000000u;
      key = ((unsigned long long)ub << 32) | (unsigned)listj[(size_t)row * SLOTS + sl];
    }
    keys[rr][sl] = key;
  }
  __syncthreads();
  int* outp = idxout + (size_t)(r0 + t) * KNN;
  for (int sel = 0; sel < KNN; ++sel) {
    unsigned long long best = ~0ULL;
    int bs = 0;
#pragma unroll 8
    for (int sl = 0; sl < SLOTS; ++sl) {
      const unsigned long long k2 = keys[t][sl];
      if (k2 < best) { best = k2; bs = sl; }
    }
    keys[t][bs] = ~0ULL;
    outp[sel] = (int)(best & 0xFFFFFFFFu);
  }
}

// ---------------------------------------------------------------------------
// EdgeConv, BIT-EXACT serial semantics per (o, n, k):
//   y = sum_c W[o,c]*ctr[c]  (prefix P)  then  += W[o,64+c]*(nb[c]-ctr[c]).
// ---------------------------------------------------------------------------

// Layer 1 (cin=3): wave per point, lane = output o.
__global__ __launch_bounds__(256) void ec_layer1(
    const float* __restrict__ pts, const int* __restrict__ idx,
    const float* __restrict__ w, const float* __restrict__ s,
    const float* __restrict__ bi, float* __restrict__ cat) {
  const int b = blockIdx.y;
  const int n = blockIdx.x * 4 + (threadIdx.x >> 6);
  const int o = threadIdx.x & 63;
  const float* p = pts + (size_t)b * 3 * N;
  const float xix = p[n], xiy = p[N + n], xiz = p[2 * N + n];
  const float* wr = w + o * 6;
  const float w0 = wr[0], w1 = wr[1], w2 = wr[2], w3 = wr[3], w4 = wr[4], w5 = wr[5];
  float P = mulrn(w0, xix);
  P = addrn(P, mulrn(w1, xiy));
  P = addrn(P, mulrn(w2, xiz));
  const float so = s[o], bo = bi[o];
  const int* ip = idx + ((size_t)b * N + n) * KNN;
  float m = 0.0f;
#pragma unroll 4
  for (int k = 0; k < KNN; ++k) {
    int j = ip[k];
    if ((unsigned)j >= (unsigned)N) j = n;
    const float ex = subrn(p[j], xix);
    const float ey = subrn(p[N + j], xiy);
    const float ez = subrn(p[2 * N + j], xiz);
    float acc = addrn(P, mulrn(w3, ex));
    acc = addrn(acc, mulrn(w4, ey));
    acc = addrn(acc, mulrn(w5, ez));
    m = fmaxf(m, addrn(mulrn(so, acc), bo));
  }
  cat[((size_t)b * N + n) * 320 + o] = m;
}

// 64-in/64-out EdgeConv layer, PHASE-SPLIT:
//  A) stage W to LDS, B) per-lane wreg + serial prefix P, C) barrier, then
//  e-vectors for all 10 neighbor-pairs written to LDS (aliased over W region),
//  D) pure read+MAC phase with 10 independent pk chains.
//  NOTE: plain launch_bounds(256) — round 8's (256,4) forced wreg spill to
//  scratch (VGPR 64, 2.4 GB HBM scratch traffic). LDS (34 KB) already caps
//  occupancy at 4 blocks/CU; let the allocator use ~130 VGPRs.
__global__ __launch_bounds__(256) void ec_layer64(
    const float* __restrict__ cat, int inoff, const int* __restrict__ idx,
    const float* __restrict__ w, const float* __restrict__ s,
    const float* __restrict__ bi, float* __restrict__ catout, int outoff) {
  __shared__ float wst[64 * 130];   // 33,280 B (aliased as est in phase C/D)
  __shared__ float xibuf[4][64];    // 1 KB
  for (int l = threadIdx.x; l < 64 * 128; l += 256) {
    wst[(l >> 7) * 130 + (l & 127)] = w[l];
  }
  __syncthreads();
  const int b = blockIdx.y;
  const int wv = threadIdx.x >> 6;
  const int n = blockIdx.x * 4 + wv;
  const int o = threadIdx.x & 63;
  // second-half weights -> registers
  float wreg[64];
#pragma unroll
  for (int c = 0; c < 64; ++c) wreg[c] = wst[o * 130 + 64 + c];
  const float xi = cat[((size_t)b * N + n) * 320 + inoff + o];
  xibuf[wv][o] = xi;
  // prefix P = serial sum_{c<64} W[o][c] * x_i[c]  (x_i broadcast from xibuf)
  float P;
  {
    const float4* x4 = (const float4*)&xibuf[wv][0];
    const float4 v0 = x4[0];
    P = mulrn(wst[o * 130 + 0], v0.x);
    P = addrn(P, mulrn(wst[o * 130 + 1], v0.y));
    P = addrn(P, mulrn(wst[o * 130 + 2], v0.z));
    P = addrn(P, mulrn(wst[o * 130 + 3], v0.w));
#pragma unroll
    for (int c4 = 1; c4 < 16; ++c4) {
      const float4 v = x4[c4];
      P = addrn(P, mulrn(wst[o * 130 + 4 * c4 + 0], v.x));
      P = addrn(P, mulrn(wst[o * 130 + 4 * c4 + 1], v.y));
      P = addrn(P, mulrn(wst[o * 130 + 4 * c4 + 2], v.z));
      P = addrn(P, mulrn(wst[o * 130 + 4 * c4 + 3], v.w));
    }
  }
  __syncthreads();  // all waves done with wst -> safe to alias as est
  // est[wv][kp][c]: v2f e-vector for pair kp; stride 66 v2f (528 B, 16B-aligned)
  v2f* est = (v2f*)wst;
  v2f* myest = est + (size_t)(wv * 10) * 66;
  const int* ip = idx + ((size_t)b * N + n) * KNN;
  const float* catb = cat + (size_t)b * N * 320 + inoff + o;
  // phase C: gathers pipelined 4 pairs at a time (bounded live ranges)
#pragma unroll 4
  for (int kp = 0; kp < 10; ++kp) {
    int j0 = ip[2 * kp];
    int j1 = ip[2 * kp + 1];
    if ((unsigned)j0 >= (unsigned)N) j0 = n;
    if ((unsigned)j1 >= (unsigned)N) j1 = n;
    const float xj0 = catb[(size_t)j0 * 320];
    const float xj1 = catb[(size_t)j1 * 320];
    myest[kp * 66 + o] = (v2f){subrn(xj0, xi), subrn(xj1, xi)};
  }
  // phase D: 10 independent serial-c chains (same-wave LDS, lgkmcnt-ordered)
  const float so = s[o], bo = bi[o];
  float m = 0.0f;
#pragma unroll 2
  for (int kp = 0; kp < 10; ++kp) {
    const float4* e4 = (const float4*)(myest + kp * 66);  // 2 v2f per read
    v2f acc = (v2f){P, P};
#pragma unroll
    for (int r = 0; r < 32; ++r) {
      const float4 q = e4[r];  // broadcast: e[2r] = (q.x,q.y), e[2r+1] = (q.z,q.w)
      acc = addrn2(acc, mulrn2((v2f){wreg[2 * r], wreg[2 * r]}, (v2f){q.x, q.y}));
      acc = addrn2(acc, mulrn2((v2f){wreg[2 * r + 1], wreg[2 * r + 1]}, (v2f){q.z, q.w}));
    }
    const v2f vv = addrn2(mulrn2((v2f){so, so}, acc), (v2f){bo, bo});
    m = fmaxf(m, fmaxf(vv.x, vv.y));
  }
  catout[((size_t)b * N + n) * 320 + outoff + o] = m;
}

// ---------------------------------------------------------------------------
// Local layer: loc[o][n] = relu(s*<W[o,:],cat[n,:]>+b), serial ascending c,
// output-pair pk-packed, b128 LDS fragments (4-consecutive mapping):
//   points  = 64e' + 4g + pi  (e'∈{0,1}, pi∈0..3)
//   outputs = 64f' + 4h + c   (f'∈{0,1}, c∈0..3)
// Register-prefetch double-buffered staging.
// ---------------------------------------------------------------------------
__global__ __launch_bounds__(256) void local_gemm(
    const float* __restrict__ cat, const float* __restrict__ w,
    const float* __restrict__ s, const float* __restrict__ bi,
    float* __restrict__ pval, int* __restrict__ pidx) {
  constexpr int KC = 32;
  constexpr int XS = 132;  // 16B-aligned rows; b128 frag reads conflict-free
  __shared__ float smem[KC * XS * 2];  // 33,792 B
  float* xs = smem;
  float* wsd = smem + KC * XS;
  const int t = threadIdx.x;
  const int q0 = blockIdx.x * 128;
  const int ptile = blockIdx.y;
  const size_t pt0 = (size_t)ptile * 128;
  const int g = t & 15;   // point frag base 4g
  const int h = t >> 4;   // output frag base 4h
  v2f acc2[2][2][4][2];   // [e'][f'][pi][u] -> outputs 64f'+4h+2u(+1)
#pragma unroll
  for (int ep = 0; ep < 2; ++ep)
#pragma unroll
    for (int fp = 0; fp < 2; ++fp)
#pragma unroll
      for (int pi = 0; pi < 4; ++pi)
#pragma unroll
        for (int u = 0; u < 2; ++u) acc2[ep][fp][pi][u] = (v2f){0.f, 0.f};

  const int lk = t & 31;
  const int lp = t >> 5;
  const float* catp = cat + pt0 * 320 + lk;
  const float* wp = w + (size_t)q0 * 320 + lk;
  float rx[16], rw[16];
#pragma unroll
  for (int i = 0; i < 16; ++i) rx[i] = catp[(size_t)(lp + 8 * i) * 320];
#pragma unroll
  for (int i = 0; i < 16; ++i) rw[i] = wp[(size_t)(lp + 8 * i) * 320];

  for (int kc = 0; kc < 320; kc += KC) {
#pragma unroll
    for (int i = 0; i < 16; ++i) xs[lk * XS + lp + 8 * i] = rx[i];
#pragma unroll
    for (int i = 0; i < 16; ++i) wsd[lk * XS + lp + 8 * i] = rw[i];
    __syncthreads();
    if (kc + KC < 320) {  // prefetch next chunk into registers
      const int ko = kc + KC;
#pragma unroll
      for (int i = 0; i < 16; ++i) rx[i] = catp[(size_t)(lp + 8 * i) * 320 + ko];
#pragma unroll
      for (int i = 0; i < 16; ++i) rw[i] = wp[(size_t)(lp + 8 * i) * 320 + ko];
    }
#pragma unroll
    for (int k = 0; k < KC; ++k) {
      float4 xf[2], wf[2];
#pragma unroll
      for (int ep = 0; ep < 2; ++ep)
        xf[ep] = *(const float4*)&xs[k * XS + 64 * ep + 4 * g];
#pragma unroll
      for (int fp = 0; fp < 2; ++fp)
        wf[fp] = *(const float4*)&wsd[k * XS + 64 * fp + 4 * h];
#pragma unroll
      for (int ep = 0; ep < 2; ++ep) {
        const float xv[4] = {xf[ep].x, xf[ep].y, xf[ep].z, xf[ep].w};
#pragma unroll
        for (int fp = 0; fp < 2; ++fp) {
          const v2f w0 = (v2f){wf[fp].x, wf[fp].y};
          const v2f w1 = (v2f){wf[fp].z, wf[fp].w};
#pragma unroll
          for (int pi = 0; pi < 4; ++pi) {
            const v2f xx = (v2f){xv[pi], xv[pi]};
            acc2[ep][fp][pi][0] = addrn2(acc2[ep][fp][pi][0], mulrn2(w0, xx));
            acc2[ep][fp][pi][1] = addrn2(acc2[ep][fp][pi][1], mulrn2(w1, xx));
          }
        }
      }
    }
    __syncthreads();
  }
  // epilogue: relu(s*acc+b), per-thread argmax over 8 points in ascending
  // point order (e' major, pi minor -> ascending) = first occurrence.
  const int bb = ptile >> 5;
  const int blk = ptile & 31;
  float mv[8];
  int mi[8];
#pragma unroll
  for (int fp = 0; fp < 2; ++fp)
#pragma unroll
    for (int c = 0; c < 4; ++c) {
      const int f = fp * 4 + c;            // local slot
      const int cl = 64 * fp + 4 * h + c;  // output index
      const float sc = s[q0 + cl];
      const float bc = bi[q0 + cl];
      mv[f] = -1.f;
      mi[f] = 0;
#pragma unroll
      for (int ep = 0; ep < 2; ++ep)
#pragma unroll
        for (int pi = 0; pi < 4; ++pi) {
          const v2f a2 = acc2[ep][fp][pi][c >> 1];
          const float a = (c & 1) ? a2.y : a2.x;
          const float v = fmaxf(addrn(mulrn(sc, a), bc), 0.f);
          if (v > mv[f]) { mv[f] = v; mi[f] = 64 * ep + 4 * g + pi; }
        }
    }
  __syncthreads();
  float* smv = smem;
  int* smi = (int*)(smem + 16 * 132);
#pragma unroll
  for (int fp = 0; fp < 2; ++fp)
#pragma unroll
    for (int c = 0; c < 4; ++c) {
      const int cl = 64 * fp + 4 * h + c;
      smv[g * 132 + cl] = mv[fp * 4 + c];
      smi[g * 132 + cl] = mi[fp * 4 + c];
    }
  __syncthreads();
  if (t < 128) {
    float best = smv[t];
    int bidx = smi[t];
    for (int gg = 1; gg < 16; ++gg) {
      const float v = smv[gg * 132 + t];
      const int vi = smi[gg * 132 + t];
      // candidates g-interleaved: ties resolve to SMALLEST point idx
      if (v > best || (v == best && vi < bidx)) { best = v; bidx = vi; }
    }
    const int n_l = blk * 128 + bidx;
    const size_t po = ((size_t)bb * 1024 + q0 + t) * 32 + blk;
    pval[po] = best;
    pidx[po] = n_l;
  }
}

__global__ __launch_bounds__(256) void final_reduce(
    const float* __restrict__ pval, const int* __restrict__ pidx,
    float* __restrict__ glob, float* __restrict__ oidx) {
  const int o = blockIdx.x * 256 + threadIdx.x;  // 8192 = B*1024
  const float* pv = pval + (size_t)o * 32;
  const int* pi = pidx + (size_t)o * 32;
  float best = pv[0];
  int bi = pi[0];
  for (int k = 1; k < 32; ++k) {
    const float v = pv[k];
    // tiles are ascending disjoint point ranges: strict > = first occurrence
    if (v > best) { best = v; bi = pi[k]; }
  }
  glob[o] = best;
  oidx[o] = (float)bi;
}

template <int KIN, int OUTS>
__global__ __launch_bounds__(256) void dense_wave(
    const float* __restrict__ in, const float* __restrict__ w,
    const float* __restrict__ s, const float* __restrict__ bi,
    float* __restrict__ out) {
  const int wid = (blockIdx.x * 256 + threadIdx.x) >> 6;
  const int lane = threadIdx.x & 63;
  const int b = wid / OUTS;
  const int o = wid % OUTS;
  const float* ip = in + (size_t)b * KIN;
  const float* wr = w + (size_t)o * KIN;
  float acc = 0.f;
  for (int k = lane; k < KIN; k += 64) acc = fmaf(wr[k], ip[k], acc);
#pragma unroll
  for (int off = 32; off; off >>= 1) acc += __shfl_down(acc, off);
  if (lane == 0) out[(size_t)b * OUTS + o] = fmaxf(fmaf(s[o], acc, bi[o]), 0.f);
}

extern "C" void kernel_launch(void* const* d_in, const int* in_sizes, int n_in,
                              void* d_out, int out_size, void* d_ws, size_t ws_size,
                              hipStream_t stream) {
  (void)in_sizes; (void)n_in; (void)out_size; (void)ws_size;
  const float* pts = (const float*)d_in[0];
  const float* ec_w[4] = {(const float*)d_in[1], (const float*)d_in[4],
                          (const float*)d_in[7], (const float*)d_in[10]};
  const float* ec_s[4] = {(const float*)d_in[2], (const float*)d_in[5],
                          (const float*)d_in[8], (const float*)d_in[11]};
  const float* ec_b[4] = {(const float*)d_in[3], (const float*)d_in[6],
                          (const float*)d_in[9], (const float*)d_in[12]};
  const float* local_w = (const float*)d_in[13];
  const float* local_s = (const float*)d_in[14];
  const float* local_b = (const float*)d_in[15];
  const float* g_w0 = (const float*)d_in[16];
  const float* g_s0 = (const float*)d_in[17];
  const float* g_b0 = (const float*)d_in[18];
  const float* g_w1 = (const float*)d_in[19];
  const float* g_s1 = (const float*)d_in[20];
  const float* g_b1 = (const float*)d_in[21];

  char* ws = (char*)d_ws;
  int* idxbuf = (int*)(ws + OFF_IDX);
  float* cat = (float*)(ws + OFF_CAT);
  float* pv = (float*)(ws + OFF_PV);
  int* pi = (int*)(ws + OFF_PI);
  float* glob = (float*)(ws + OFF_GLOB);
  float* hbuf = (float*)(ws + OFF_H);
  float* listd = (float*)(ws + OFF_LD);
  int* listj = (int*)(ws + OFF_LJ);
  int* counts = (int*)(ws + OFF_CNT);
  float* outv = (float*)d_out;   // [8][256]  fp32
  float* oidx = outv + 2048;     // [8][1024] fp32 (indices as floats)

  knn_scan<<<dim3(64, 8), 256, 0, stream>>>(pts, listd, listj, counts);
  knn_merge<<<dim3(512), 64, 0, stream>>>(listd, listj, counts, idxbuf);

  // layer 1 (3 -> 64)
  ec_layer1<<<dim3(1024, 8), 256, 0, stream>>>(pts, idxbuf, ec_w[0], ec_s[0], ec_b[0], cat);
  // layer 2 (64 -> 64)
  ec_layer64<<<dim3(1024, 8), 256, 0, stream>>>(cat, 0, idxbuf, ec_w[1], ec_s[1], ec_b[1], cat, 64);
  // layer 3 (64 -> 64)
  ec_layer64<<<dim3(1024, 8), 256, 0, stream>>>(cat, 64, idxbuf, ec_w[2], ec_s[2], ec_b[2], cat, 128);
  // layer 4 (64 -> 128), two 64-output halves (outputs independent -> exact)
  ec_layer64<<<dim3(1024, 8), 256, 0, stream>>>(cat, 128, idxbuf, ec_w[3], ec_s[3], ec_b[3], cat, 192);
  ec_layer64<<<dim3(1024, 8), 256, 0, stream>>>(cat, 128, idxbuf, ec_w[3] + 64 * 128,
                                                ec_s[3] + 64, ec_b[3] + 64, cat, 256);

  local_gemm<<<dim3(8, 256), 256, 0, stream>>>(cat, local_w, local_s, local_b, pv, pi);
  final_reduce<<<dim3(32), 256, 0, stream>>>(pv, pi, glob, oidx);
  dense_wave<1024, 512><<<dim3(1024), 256, 0, stream>>>(glob, g_w0, g_s0, g_b0, hbuf);
  dense_wave<512, 256><<<dim3(512), 256, 0, stream>>>(hbuf, g_w1, g_s1, g_b1, outv);
}

// Round 10
// 1500.352 us; speedup vs baseline: 2.3323x; 1.3607x over previous
//
#include <hip/hip_runtime.h>
#include <hip/hip_bf16.h>

namespace {
constexpr int B = 8;
constexpr int N = 4096;
constexpr int KNN = 20;
constexpr int NSEG = 4;
constexpr int SEGLEN = N / NSEG;   // 1024
constexpr int CAP = 24;
constexpr int SLOTS = NSEG * CAP;  // 96

// workspace layout (bytes)
constexpr size_t OFF_IDX  = 0;                          // int [B][N][KNN]
constexpr size_t SZ_IDX   = (size_t)B * N * KNN * 4;
constexpr size_t OFF_T    = OFF_IDX + SZ_IDX;           // knn scratch region
constexpr size_t SZ_T     = (size_t)B * N * 128 * 4;
constexpr size_t OFF_CAT  = OFF_T + SZ_T;               // float [B][N][320]
constexpr size_t SZ_CAT   = (size_t)B * N * 320 * 4;
constexpr size_t OFF_PV   = OFF_CAT + SZ_CAT;           // float [B][1024][32]
constexpr size_t SZ_PV    = (size_t)B * 1024 * 32 * 4;
constexpr size_t OFF_PI   = OFF_PV + SZ_PV;             // int   [B][1024][32]
constexpr size_t OFF_GLOB = OFF_PI + SZ_PV;             // float [B][1024]
constexpr size_t OFF_H    = OFF_GLOB + (size_t)B * 1024 * 4;  // float [B][512]
// knn scratch overlaid on T + head of CAT (dead once merge completes):
constexpr size_t OFF_LD   = OFF_T;                      // float [B*N][SLOTS]
constexpr size_t SZ_LD    = (size_t)B * N * SLOTS * 4;
constexpr size_t OFF_LJ   = OFF_LD + SZ_LD;             // int   [B*N][SLOTS]
constexpr size_t OFF_CNT  = OFF_LJ + SZ_LD;             // int   [B*N][NSEG]
}  // namespace

typedef float v2f __attribute__((ext_vector_type(2)));

// Non-contractable fp32 ops: bit-exact match to np's mul-then-add serial loops.
__device__ __forceinline__ float mulrn(float a, float b) {
#pragma clang fp contract(off)
  return a * b;
}
__device__ __forceinline__ float addrn(float a, float b) {
#pragma clang fp contract(off)
  return a + b;
}
__device__ __forceinline__ float subrn(float a, float b) {
#pragma clang fp contract(off)
  return a - b;
}
// Packed (v_pk_mul_f32 / v_pk_add_f32): per-element IEEE rn == scalar ops.
__device__ __forceinline__ v2f mulrn2(v2f a, v2f b) {
#pragma clang fp contract(off)
  return a * b;
}
__device__ __forceinline__ v2f addrn2(v2f a, v2f b) {
#pragma clang fp contract(off)
  return a + b;
}

// ---------------------------------------------------------------------------
// kNN: per-thread scan of one row-segment keeping sorted top-20 distances,
// then recovery pass collects (d, j) with d <= theta in ascending-j order.
// ---------------------------------------------------------------------------
__global__ __launch_bounds__(256) void knn_scan(
    const float* __restrict__ pts,
    float* __restrict__ listd, int* __restrict__ listj, int* __restrict__ counts) {
  __shared__ float4 sp[N];  // 64 KB: (x, y, z, sq)
  const int b = blockIdx.y;
  const int tid = threadIdx.x;
  const float* px = pts + (size_t)b * 3 * N;
  for (int i = tid; i < N; i += 256) {
    const float x = px[i];
    const float y = px[N + i];
    const float z = px[2 * N + i];
    const float sq = addrn(addrn(mulrn(x, x), mulrn(y, y)), mulrn(z, z));
    sp[i] = make_float4(x, y, z, sq);
  }
  __syncthreads();
  const int row = blockIdx.x * 64 + (tid & 63);
  const int seg = tid >> 6;
  const float4 q = sp[row];
  float ds[KNN];
#pragma unroll
  for (int t = 0; t < KNN; ++t) ds[t] = 3.0e38f;
  const int j0 = seg * SEGLEN;
#pragma unroll 2
  for (int jj = 0; jj < SEGLEN; jj += 2) {
    const float4 c0 = sp[j0 + jj];
    const float4 c1 = sp[j0 + jj + 1];
    v2f t0 = mulrn2((v2f){q.x, q.x}, (v2f){c0.x, c1.x});
    t0 = addrn2(t0, mulrn2((v2f){q.y, q.y}, (v2f){c0.y, c1.y}));
    t0 = addrn2(t0, mulrn2((v2f){q.z, q.z}, (v2f){c0.z, c1.z}));
    v2f d2 = addrn2((v2f){q.w, q.w}, (v2f){c0.w, c1.w});
    d2 = d2 - mulrn2((v2f){2.0f, 2.0f}, t0);
#pragma unroll
    for (int u = 0; u < 2; ++u) {
      const float d = u ? d2.y : d2.x;
      if (d < ds[KNN - 1]) {
        float cur = d;
#pragma unroll
        for (int t = 0; t < KNN; ++t) {
          const float lo = fminf(cur, ds[t]);
          cur = fmaxf(cur, ds[t]);
          ds[t] = lo;
        }
      }
    }
  }
  const float th = ds[KNN - 1];
  const int rbase = (b * N + row) * NSEG + seg;
  float* ld = listd + (size_t)(b * N + row) * SLOTS + seg * CAP;
  int* lj = listj + (size_t)(b * N + row) * SLOTS + seg * CAP;
  int cnt = 0;
#pragma unroll 2
  for (int jj = 0; jj < SEGLEN; jj += 2) {
    const float4 c0 = sp[j0 + jj];
    const float4 c1 = sp[j0 + jj + 1];
    v2f t0 = mulrn2((v2f){q.x, q.x}, (v2f){c0.x, c1.x});
    t0 = addrn2(t0, mulrn2((v2f){q.y, q.y}, (v2f){c0.y, c1.y}));
    t0 = addrn2(t0, mulrn2((v2f){q.z, q.z}, (v2f){c0.z, c1.z}));
    v2f d2 = addrn2((v2f){q.w, q.w}, (v2f){c0.w, c1.w});
    d2 = d2 - mulrn2((v2f){2.0f, 2.0f}, t0);
#pragma unroll
    for (int u = 0; u < 2; ++u) {
      const float d = u ? d2.y : d2.x;
      if (d <= th && cnt < CAP) {
        ld[cnt] = d;
        lj[cnt] = j0 + jj + u;
        ++cnt;
      }
    }
  }
  counts[rbase] = cnt;
}

// Merge: per row, select 20 lexicographically-smallest (dist, j) from <=96
// candidates via monotone uint64 keys.
__global__ __launch_bounds__(64) void knn_merge(
    const float* __restrict__ listd, const int* __restrict__ listj,
    const int* __restrict__ counts, int* __restrict__ idxout) {
  __shared__ unsigned long long keys[64][SLOTS + 1];  // 49,664 B
  const int r0 = blockIdx.x * 64;
  const int t = threadIdx.x;
  for (int i = t; i < 64 * SLOTS; i += 64) {
    const int rr = i / SLOTS;
    const int sl = i % SLOTS;
    const int seg = sl / CAP;
    const int e = sl % CAP;
    const int row = r0 + rr;
    unsigned long long key = 0xFFFFFFFE00000000ULL | (unsigned)row;  // fallback: self
    if (e < counts[row * NSEG + seg]) {
      const float d = listd[(size_t)row * SLOTS + sl];
      unsigned ub = __float_as_uint(d);
      ub ^= (ub & 0x80000000u) ? 0xFFFFFFFFu : 0x80000000u;
      key = ((unsigned long long)ub << 32) | (unsigned)listj[(size_t)row * SLOTS + sl];
    }
    keys[rr][sl] = key;
  }
  __syncthreads();
  int* outp = idxout + (size_t)(r0 + t) * KNN;
  for (int sel = 0; sel < KNN; ++sel) {
    unsigned long long best = ~0ULL;
    int bs = 0;
#pragma unroll 8
    for (int sl = 0; sl < SLOTS; ++sl) {
      const unsigned long long k2 = keys[t][sl];
      if (k2 < best) { best = k2; bs = sl; }
    }
    keys[t][bs] = ~0ULL;
    outp[sel] = (int)(best & 0xFFFFFFFFu);
  }
}

// ---------------------------------------------------------------------------
// EdgeConv, BIT-EXACT serial semantics per (o, n, k):
//   y = sum_c W1[o,c]*x_i[c]  (prefix P)  then  += W2[o,c]*(x_j[c]-x_i[c]),
// both in ascending c with a single accumulator.
// ---------------------------------------------------------------------------

// Layer 1 (cin=3): wave per point, lane = output o.
__global__ __launch_bounds__(256) void ec_layer1(
    const float* __restrict__ pts, const int* __restrict__ idx,
    const float* __restrict__ w, const float* __restrict__ s,
    const float* __restrict__ bi, float* __restrict__ cat) {
  const int b = blockIdx.y;
  const int n = blockIdx.x * 4 + (threadIdx.x >> 6);
  const int o = threadIdx.x & 63;
  const float* p = pts + (size_t)b * 3 * N;
  const float xix = p[n], xiy = p[N + n], xiz = p[2 * N + n];
  const float* wr = w + o * 6;
  const float w0 = wr[0], w1 = wr[1], w2 = wr[2], w3 = wr[3], w4 = wr[4], w5 = wr[5];
  float P = mulrn(w0, xix);
  P = addrn(P, mulrn(w1, xiy));
  P = addrn(P, mulrn(w2, xiz));
  const float so = s[o], bo = bi[o];
  const int* ip = idx + ((size_t)b * N + n) * KNN;
  float m = 0.0f;
#pragma unroll 4
  for (int k = 0; k < KNN; ++k) {
    int j = ip[k];
    if ((unsigned)j >= (unsigned)N) j = n;
    const float ex = subrn(p[j], xix);
    const float ey = subrn(p[N + j], xiy);
    const float ez = subrn(p[2 * N + j], xiz);
    float acc = addrn(P, mulrn(w3, ex));
    acc = addrn(acc, mulrn(w4, ey));
    acc = addrn(acc, mulrn(w5, ez));
    m = fmaxf(m, addrn(mulrn(so, acc), bo));
  }
  cat[((size_t)b * N + n) * 320 + o] = m;
}

// 64-in/64-out EdgeConv as an EDGE-GEMM. Block: 8 points x 24 edge-slots
// (20 real + 4 duplicates of slot 0 — duplicates never change the max)
// = 192 edges x 64 outputs. Per thread: 12 edges x 4 outputs, acc init = P,
// ascending-c pk-MACs (per-element rn -> bit-exact serial chain).
__global__ __launch_bounds__(256) void ec_edge(
    const float* __restrict__ cat, int inoff, const int* __restrict__ idx,
    const float* __restrict__ w, const float* __restrict__ s,
    const float* __restrict__ bi, float* __restrict__ catout, int outoff) {
  constexpr int EST = 196;          // e-chunk row stride (floats)
  __shared__ float U[64 * 65];      // 16.6 KB: Wl1 -> e-chunk -> gmax (phased)
  __shared__ float xis[8][64];      // 2 KB
  __shared__ float Pt[8][68];       // 2.2 KB
  __shared__ float Wl2[16][68];     // 4.4 KB
  __shared__ int jl[192];
  const int t = threadIdx.x;
  const int b = blockIdx.y;
  const int n0 = blockIdx.x * 8;
  const size_t bN = (size_t)b * N;
  // stage Wl1 (first 64 cols of each 128-wide W row), coalesced
#pragma unroll
  for (int q = 0; q < 16; ++q) {
    const int l = t + 256 * q;  // 0..4095
    U[(l >> 6) * 65 + (l & 63)] = w[(l >> 6) * 128 + (l & 63)];
  }
  // stage xi[8][64]
#pragma unroll
  for (int q = 0; q < 2; ++q) {
    const int p = (t >> 6) + 4 * q;
    const int c = t & 63;
    xis[p][c] = cat[(bN + n0 + p) * 320 + inoff + c];
  }
  // edge slot -> neighbor index (slots 20..23 duplicate slot 0)
  if (t < 192) {
    const int p = t / 24;
    const int k = t % 24;
    int j = idx[(bN + n0 + p) * KNN + (k < KNN ? k : 0)];
    if ((unsigned)j >= (unsigned)N) j = n0 + p;  // firewall
    jl[t] = j;
  }
  __syncthreads();
  // prefix P[p][o]: serial sum_{c<64} W1[o][c]*x_i[c] (two p per thread)
  {
    const int o = t & 63;
    const int p0 = t >> 6;
    float P0, P1;
    {
      const float w0 = U[o * 65];
      P0 = mulrn(w0, xis[p0][0]);
      P1 = mulrn(w0, xis[p0 + 4][0]);
    }
#pragma unroll
    for (int c = 1; c < 64; ++c) {
      const float wc = U[o * 65 + c];
      P0 = addrn(P0, mulrn(wc, xis[p0][c]));
      P1 = addrn(P1, mulrn(wc, xis[p0 + 4][c]));
    }
    Pt[p0][o] = P0;
    Pt[p0 + 4][o] = P1;
  }
  __syncthreads();  // Pt ready; U (Wl1) free for reuse after this point
  const int g = t & 15;   // edge-frag lane: edges 64i + 4g + e
  const int h = t >> 4;   // output-frag lane: outputs 4h + u
  v2f acc[3][4][2];
#pragma unroll
  for (int i = 0; i < 3; ++i) {
    const int grp = 16 * i + g;
    const int p = grp / 6;  // each 4-edge group lies within one point
    const float4 Pv = *(const float4*)&Pt[p][4 * h];
#pragma unroll
    for (int e = 0; e < 4; ++e) {
      acc[i][e][0] = (v2f){Pv.x, Pv.y};
      acc[i][e][1] = (v2f){Pv.z, Pv.w};
    }
  }
  const float* catb = cat + inoff;
  for (int kc = 0; kc < 64; kc += 16) {
    __syncthreads();  // previous chunk's readers done before restaging U
    // stage Wl2[k][o], k = kc..kc+15 (transposed)
    {
      const int o = t >> 2;
      const int cq = t & 3;
      const float4 wv = *(const float4*)&w[o * 128 + 64 + kc + 4 * cq];
      Wl2[4 * cq + 0][o] = wv.x;
      Wl2[4 * cq + 1][o] = wv.y;
      Wl2[4 * cq + 2][o] = wv.z;
      Wl2[4 * cq + 3][o] = wv.w;
    }
    // stage e[cl][sl] = x_j[c] - x_i[c] (exact subrn), c-major
#pragma unroll
    for (int q = 0; q < 3; ++q) {
      const int sl = 64 * q + (t >> 2);
      const int cq = t & 3;
      const int p = sl / 24;
      const int j = jl[sl];
      const float4 xj = *(const float4*)&catb[(bN + j) * 320 + kc + 4 * cq];
      const float4 xv = *(const float4*)&xis[p][kc + 4 * cq];
      U[(4 * cq + 0) * EST + sl] = subrn(xj.x, xv.x);
      U[(4 * cq + 1) * EST + sl] = subrn(xj.y, xv.y);
      U[(4 * cq + 2) * EST + sl] = subrn(xj.z, xv.z);
      U[(4 * cq + 3) * EST + sl] = subrn(xj.w, xv.w);
    }
    __syncthreads();
#pragma unroll
    for (int k = 0; k < 16; ++k) {
      const float4 wf = *(const float4*)&Wl2[k][4 * h];
      const v2f w01 = (v2f){wf.x, wf.y};
      const v2f w23 = (v2f){wf.z, wf.w};
#pragma unroll
      for (int i = 0; i < 3; ++i) {
        const float4 ef = *(const float4*)&U[k * EST + 64 * i + 4 * g];
        const float ev[4] = {ef.x, ef.y, ef.z, ef.w};
#pragma unroll
        for (int e = 0; e < 4; ++e) {
          const v2f xx = (v2f){ev[e], ev[e]};
          acc[i][e][0] = addrn2(acc[i][e][0], mulrn2(w01, xx));
          acc[i][e][1] = addrn2(acc[i][e][1], mulrn2(w23, xx));
        }
      }
    }
  }
  __syncthreads();  // all MAC reads of U done before gmax writes
  // epilogue: v = relu(s*acc + b) per edge; group-max over each 4-edge group
  {
    const float4 sv = *(const float4*)&s[4 * h];
    const float4 bv = *(const float4*)&bi[4 * h];
    const float sc[4] = {sv.x, sv.y, sv.z, sv.w};
    const float bc[4] = {bv.x, bv.y, bv.z, bv.w};
#pragma unroll
    for (int i = 0; i < 3; ++i) {
      const int grp = 16 * i + g;
      float gm[4] = {0.f, 0.f, 0.f, 0.f};  // relu floor
#pragma unroll
      for (int e = 0; e < 4; ++e) {
#pragma unroll
        for (int u = 0; u < 4; ++u) {
          const v2f a2 = acc[i][e][u >> 1];
          const float a = (u & 1) ? a2.y : a2.x;
          const float v = fmaxf(addrn(mulrn(sc[u], a), bc[u]), 0.f);
          gm[u] = fmaxf(gm[u], v);
        }
      }
#pragma unroll
      for (int u = 0; u < 4; ++u) U[grp * 68 + 4 * h + u] = gm[u];
    }
  }
  __syncthreads();
  // per (p, o): max over the point's 6 groups -> cat
#pragma unroll
  for (int q = 0; q < 2; ++q) {
    const int o = t & 63;
    const int p = (t >> 6) + 4 * q;
    float m = U[(p * 6) * 68 + o];
#pragma unroll
    for (int gi = 1; gi < 6; ++gi) m = fmaxf(m, U[(p * 6 + gi) * 68 + o]);
    catout[(bN + n0 + p) * 320 + outoff + o] = m;
  }
}

// ---------------------------------------------------------------------------
// Local layer: loc[o][n] = relu(s*<W[o,:],cat[n,:]>+b), serial ascending c,
// output-pair pk-packed, b128 LDS fragments. Register-prefetch double-buffer.
// ---------------------------------------------------------------------------
__global__ __launch_bounds__(256) void local_gemm(
    const float* __restrict__ cat, const float* __restrict__ w,
    const float* __restrict__ s, const float* __restrict__ bi,
    float* __restrict__ pval, int* __restrict__ pidx) {
  constexpr int KC = 32;
  constexpr int XS = 132;
  __shared__ float smem[KC * XS * 2];  // 33,792 B
  float* xs = smem;
  float* wsd = smem + KC * XS;
  const int t = threadIdx.x;
  const int q0 = blockIdx.x * 128;
  const int ptile = blockIdx.y;
  const size_t pt0 = (size_t)ptile * 128;
  const int g = t & 15;
  const int h = t >> 4;
  v2f acc2[2][2][4][2];
#pragma unroll
  for (int ep = 0; ep < 2; ++ep)
#pragma unroll
    for (int fp = 0; fp < 2; ++fp)
#pragma unroll
      for (int pi = 0; pi < 4; ++pi)
#pragma unroll
        for (int u = 0; u < 2; ++u) acc2[ep][fp][pi][u] = (v2f){0.f, 0.f};

  const int lk = t & 31;
  const int lp = t >> 5;
  const float* catp = cat + pt0 * 320 + lk;
  const float* wp = w + (size_t)q0 * 320 + lk;
  float rx[16], rw[16];
#pragma unroll
  for (int i = 0; i < 16; ++i) rx[i] = catp[(size_t)(lp + 8 * i) * 320];
#pragma unroll
  for (int i = 0; i < 16; ++i) rw[i] = wp[(size_t)(lp + 8 * i) * 320];

  for (int kc = 0; kc < 320; kc += KC) {
#pragma unroll
    for (int i = 0; i < 16; ++i) xs[lk * XS + lp + 8 * i] = rx[i];
#pragma unroll
    for (int i = 0; i < 16; ++i) wsd[lk * XS + lp + 8 * i] = rw[i];
    __syncthreads();
    if (kc + KC < 320) {
      const int ko = kc + KC;
#pragma unroll
      for (int i = 0; i < 16; ++i) rx[i] = catp[(size_t)(lp + 8 * i) * 320 + ko];
#pragma unroll
      for (int i = 0; i < 16; ++i) rw[i] = wp[(size_t)(lp + 8 * i) * 320 + ko];
    }
#pragma unroll
    for (int k = 0; k < KC; ++k) {
      float4 xf[2], wf[2];
#pragma unroll
      for (int ep = 0; ep < 2; ++ep)
        xf[ep] = *(const float4*)&xs[k * XS + 64 * ep + 4 * g];
#pragma unroll
      for (int fp = 0; fp < 2; ++fp)
        wf[fp] = *(const float4*)&wsd[k * XS + 64 * fp + 4 * h];
#pragma unroll
      for (int ep = 0; ep < 2; ++ep) {
        const float xv[4] = {xf[ep].x, xf[ep].y, xf[ep].z, xf[ep].w};
#pragma unroll
        for (int fp = 0; fp < 2; ++fp) {
          const v2f w0 = (v2f){wf[fp].x, wf[fp].y};
          const v2f w1 = (v2f){wf[fp].z, wf[fp].w};
#pragma unroll
          for (int pi = 0; pi < 4; ++pi) {
            const v2f xx = (v2f){xv[pi], xv[pi]};
            acc2[ep][fp][pi][0] = addrn2(acc2[ep][fp][pi][0], mulrn2(w0, xx));
            acc2[ep][fp][pi][1] = addrn2(acc2[ep][fp][pi][1], mulrn2(w1, xx));
          }
        }
      }
    }
    __syncthreads();
  }
  const int bb = ptile >> 5;
  const int blk = ptile & 31;
  float mv[8];
  int mi[8];
#pragma unroll
  for (int fp = 0; fp < 2; ++fp)
#pragma unroll
    for (int c = 0; c < 4; ++c) {
      const int f = fp * 4 + c;
      const int cl = 64 * fp + 4 * h + c;
      const float sc = s[q0 + cl];
      const float bc = bi[q0 + cl];
      mv[f] = -1.f;
      mi[f] = 0;
#pragma unroll
      for (int ep = 0; ep < 2; ++ep)
#pragma unroll
        for (int pi = 0; pi < 4; ++pi) {
          const v2f a2 = acc2[ep][fp][pi][c >> 1];
          const float a = (c & 1) ? a2.y : a2.x;
          const float v = fmaxf(addrn(mulrn(sc, a), bc), 0.f);
          if (v > mv[f]) { mv[f] = v; mi[f] = 64 * ep + 4 * g + pi; }
        }
    }
  __syncthreads();
  float* smv = smem;
  int* smi = (int*)(smem + 16 * 132);
#pragma unroll
  for (int fp = 0; fp < 2; ++fp)
#pragma unroll
    for (int c = 0; c < 4; ++c) {
      const int cl = 64 * fp + 4 * h + c;
      smv[g * 132 + cl] = mv[fp * 4 + c];
      smi[g * 132 + cl] = mi[fp * 4 + c];
    }
  __syncthreads();
  if (t < 128) {
    float best = smv[t];
    int bidx = smi[t];
    for (int gg = 1; gg < 16; ++gg) {
      const float v = smv[gg * 132 + t];
      const int vi = smi[gg * 132 + t];
      if (v > best || (v == best && vi < bidx)) { best = v; bidx = vi; }
    }
    const int n_l = blk * 128 + bidx;
    const size_t po = ((size_t)bb * 1024 + q0 + t) * 32 + blk;
    pval[po] = best;
    pidx[po] = n_l;
  }
}

__global__ __launch_bounds__(256) void final_reduce(
    const float* __restrict__ pval, const int* __restrict__ pidx,
    float* __restrict__ glob, float* __restrict__ oidx) {
  const int o = blockIdx.x * 256 + threadIdx.x;  // 8192 = B*1024
  const float* pv = pval + (size_t)o * 32;
  const int* pi = pidx + (size_t)o * 32;
  float best = pv[0];
  int bi = pi[0];
  for (int k = 1; k < 32; ++k) {
    const float v = pv[k];
    if (v > best) { best = v; bi = pi[k]; }
  }
  glob[o] = best;
  oidx[o] = (float)bi;
}

template <int KIN, int OUTS>
__global__ __launch_bounds__(256) void dense_wave(
    const float* __restrict__ in, const float* __restrict__ w,
    const float* __restrict__ s, const float* __restrict__ bi,
    float* __restrict__ out) {
  const int wid = (blockIdx.x * 256 + threadIdx.x) >> 6;
  const int lane = threadIdx.x & 63;
  const int b = wid / OUTS;
  const int o = wid % OUTS;
  const float* ip = in + (size_t)b * KIN;
  const float* wr = w + (size_t)o * KIN;
  float acc = 0.f;
  for (int k = lane; k < KIN; k += 64) acc = fmaf(wr[k], ip[k], acc);
#pragma unroll
  for (int off = 32; off; off >>= 1) acc += __shfl_down(acc, off);
  if (lane == 0) out[(size_t)b * OUTS + o] = fmaxf(fmaf(s[o], acc, bi[o]), 0.f);
}

extern "C" void kernel_launch(void* const* d_in, const int* in_sizes, int n_in,
                              void* d_out, int out_size, void* d_ws, size_t ws_size,
                              hipStream_t stream) {
  (void)in_sizes; (void)n_in; (void)out_size; (void)ws_size;
  const float* pts = (const float*)d_in[0];
  const float* ec_w[4] = {(const float*)d_in[1], (const float*)d_in[4],
                          (const float*)d_in[7], (const float*)d_in[10]};
  const float* ec_s[4] = {(const float*)d_in[2], (const float*)d_in[5],
                          (const float*)d_in[8], (const float*)d_in[11]};
  const float* ec_b[4] = {(const float*)d_in[3], (const float*)d_in[6],
                          (const float*)d_in[9], (const float*)d_in[12]};
  const float* local_w = (const float*)d_in[13];
  const float* local_s = (const float*)d_in[14];
  const float* local_b = (const float*)d_in[15];
  const float* g_w0 = (const float*)d_in[16];
  const float* g_s0 = (const float*)d_in[17];
  const float* g_b0 = (const float*)d_in[18];
  const float* g_w1 = (const float*)d_in[19];
  const float* g_s1 = (const float*)d_in[20];
  const float* g_b1 = (const float*)d_in[21];

  char* ws = (char*)d_ws;
  int* idxbuf = (int*)(ws + OFF_IDX);
  float* cat = (float*)(ws + OFF_CAT);
  float* pv = (float*)(ws + OFF_PV);
  int* pi = (int*)(ws + OFF_PI);
  float* glob = (float*)(ws + OFF_GLOB);
  float* hbuf = (float*)(ws + OFF_H);
  float* listd = (float*)(ws + OFF_LD);
  int* listj = (int*)(ws + OFF_LJ);
  int* counts = (int*)(ws + OFF_CNT);
  float* outv = (float*)d_out;   // [8][256]  fp32
  float* oidx = outv + 2048;     // [8][1024] fp32 (indices as floats)

  knn_scan<<<dim3(64, 8), 256, 0, stream>>>(pts, listd, listj, counts);
  knn_merge<<<dim3(512), 64, 0, stream>>>(listd, listj, counts, idxbuf);

  // layer 1 (3 -> 64)
  ec_layer1<<<dim3(1024, 8), 256, 0, stream>>>(pts, idxbuf, ec_w[0], ec_s[0], ec_b[0], cat);
  // layer 2 (64 -> 64)
  ec_edge<<<dim3(512, 8), 256, 0, stream>>>(cat, 0, idxbuf, ec_w[1], ec_s[1], ec_b[1], cat, 64);
  // layer 3 (64 -> 64)
  ec_edge<<<dim3(512, 8), 256, 0, stream>>>(cat, 64, idxbuf, ec_w[2], ec_s[2], ec_b[2], cat, 128);
  // layer 4 (64 -> 128), two 64-output halves (outputs independent -> exact)
  ec_edge<<<dim3(512, 8), 256, 0, stream>>>(cat, 128, idxbuf, ec_w[3], ec_s[3], ec_b[3], cat, 192);
  ec_edge<<<dim3(512, 8), 256, 0, stream>>>(cat, 128, idxbuf, ec_w[3] + 64 * 128,
                                            ec_s[3] + 64, ec_b[3] + 64, cat, 256);

  local_gemm<<<dim3(8, 256), 256, 0, stream>>>(cat, local_w, local_s, local_b, pv, pi);
  final_reduce<<<dim3(32), 256, 0, stream>>>(pv, pi, glob, oidx);
  dense_wave<1024, 512><<<dim3(1024), 256, 0, stream>>>(glob, g_w0, g_s0, g_b0, hbuf);
  dense_wave<512, 256><<<dim3(512), 256, 0, stream>>>(hbuf, g_w1, g_s1, g_b1, outv);
}

// Round 11
// 1462.772 us; speedup vs baseline: 2.3922x; 1.0257x over previous
//
#include <hip/hip_runtime.h>
#include <hip/hip_bf16.h>

namespace {
constexpr int B = 8;
constexpr int N = 4096;
constexpr int KNN = 20;
constexpr int NSEG = 4;
constexpr int SEGLEN = N / NSEG;   // 1024
constexpr int CAP = 24;
constexpr int SLOTS = NSEG * CAP;  // 96

// workspace layout (bytes)
constexpr size_t OFF_IDX  = 0;                          // int [B][N][KNN]
constexpr size_t SZ_IDX   = (size_t)B * N * KNN * 4;
constexpr size_t OFF_T    = OFF_IDX + SZ_IDX;           // knn scratch region
constexpr size_t SZ_T     = (size_t)B * N * 128 * 4;
constexpr size_t OFF_CAT  = OFF_T + SZ_T;               // float [B][N][320]
constexpr size_t SZ_CAT   = (size_t)B * N * 320 * 4;
constexpr size_t OFF_PV   = OFF_CAT + SZ_CAT;           // float [B][1024][32]
constexpr size_t SZ_PV    = (size_t)B * 1024 * 32 * 4;
constexpr size_t OFF_PI   = OFF_PV + SZ_PV;             // int   [B][1024][32]
constexpr size_t OFF_GLOB = OFF_PI + SZ_PV;             // float [B][1024]
constexpr size_t OFF_H    = OFF_GLOB + (size_t)B * 1024 * 4;  // float [B][512]
// knn scratch overlaid on T + head of CAT (dead once merge completes):
constexpr size_t OFF_LD   = OFF_T;                      // float [B*N][SLOTS]
constexpr size_t SZ_LD    = (size_t)B * N * SLOTS * 4;
constexpr size_t OFF_LJ   = OFF_LD + SZ_LD;             // int   [B*N][SLOTS]
constexpr size_t OFF_CNT  = OFF_LJ + SZ_LD;             // int   [B*N][NSEG]
}  // namespace

typedef float v2f __attribute__((ext_vector_type(2)));

// Non-contractable fp32 ops: bit-exact match to np's mul-then-add serial loops.
__device__ __forceinline__ float mulrn(float a, float b) {
#pragma clang fp contract(off)
  return a * b;
}
__device__ __forceinline__ float addrn(float a, float b) {
#pragma clang fp contract(off)
  return a + b;
}
__device__ __forceinline__ float subrn(float a, float b) {
#pragma clang fp contract(off)
  return a - b;
}
// Packed (v_pk_mul_f32 / v_pk_add_f32): per-element IEEE rn == scalar ops.
__device__ __forceinline__ v2f mulrn2(v2f a, v2f b) {
#pragma clang fp contract(off)
  return a * b;
}
__device__ __forceinline__ v2f addrn2(v2f a, v2f b) {
#pragma clang fp contract(off)
  return a + b;
}

// ---------------------------------------------------------------------------
// kNN: 2 rows per thread (row, row+64) -> one sp[j] broadcast read serves 128
// rows per wave (halves LDS-pipe load). Sorted-20 bubble per row; recovery
// pass collects (d, j) with d <= theta in ascending-j order.
// ---------------------------------------------------------------------------
__global__ __launch_bounds__(256) void knn_scan(
    const float* __restrict__ pts,
    float* __restrict__ listd, int* __restrict__ listj, int* __restrict__ counts) {
  __shared__ float4 sp[N];  // 64 KB: (x, y, z, sq)
  const int b = blockIdx.y;
  const int tid = threadIdx.x;
  const float* px = pts + (size_t)b * 3 * N;
  for (int i = tid; i < N; i += 256) {
    const float x = px[i];
    const float y = px[N + i];
    const float z = px[2 * N + i];
    const float sq = addrn(addrn(mulrn(x, x), mulrn(y, y)), mulrn(z, z));
    sp[i] = make_float4(x, y, z, sq);
  }
  __syncthreads();
  const int row0 = blockIdx.x * 128 + (tid & 63);
  const int row1 = row0 + 64;
  const int seg = tid >> 6;
  const float4 qa = sp[row0];
  const float4 qb = sp[row1];
  float da[KNN], db[KNN];
#pragma unroll
  for (int t = 0; t < KNN; ++t) { da[t] = 3.0e38f; db[t] = 3.0e38f; }
  const int j0 = seg * SEGLEN;
#pragma unroll 2
  for (int jj = 0; jj < SEGLEN; ++jj) {
    const float4 c = sp[j0 + jj];
    v2f t0 = mulrn2((v2f){qa.x, qb.x}, (v2f){c.x, c.x});
    t0 = addrn2(t0, mulrn2((v2f){qa.y, qb.y}, (v2f){c.y, c.y}));
    t0 = addrn2(t0, mulrn2((v2f){qa.z, qb.z}, (v2f){c.z, c.z}));
    v2f d2 = addrn2((v2f){qa.w, qb.w}, (v2f){c.w, c.w});
    d2 = d2 - mulrn2((v2f){2.0f, 2.0f}, t0);
    if (d2.x < da[KNN - 1]) {
      float cur = d2.x;
#pragma unroll
      for (int t = 0; t < KNN; ++t) {
        const float lo = fminf(cur, da[t]);
        cur = fmaxf(cur, da[t]);
        da[t] = lo;
      }
    }
    if (d2.y < db[KNN - 1]) {
      float cur = d2.y;
#pragma unroll
      for (int t = 0; t < KNN; ++t) {
        const float lo = fminf(cur, db[t]);
        cur = fmaxf(cur, db[t]);
        db[t] = lo;
      }
    }
  }
  const float tha = da[KNN - 1];
  const float thb = db[KNN - 1];
  float* lda = listd + (size_t)(b * N + row0) * SLOTS + seg * CAP;
  int* lja = listj + (size_t)(b * N + row0) * SLOTS + seg * CAP;
  float* ldb = listd + (size_t)(b * N + row1) * SLOTS + seg * CAP;
  int* ljb = listj + (size_t)(b * N + row1) * SLOTS + seg * CAP;
  int ca = 0, cb = 0;
#pragma unroll 2
  for (int jj = 0; jj < SEGLEN; ++jj) {
    const float4 c = sp[j0 + jj];
    v2f t0 = mulrn2((v2f){qa.x, qb.x}, (v2f){c.x, c.x});
    t0 = addrn2(t0, mulrn2((v2f){qa.y, qb.y}, (v2f){c.y, c.y}));
    t0 = addrn2(t0, mulrn2((v2f){qa.z, qb.z}, (v2f){c.z, c.z}));
    v2f d2 = addrn2((v2f){qa.w, qb.w}, (v2f){c.w, c.w});
    d2 = d2 - mulrn2((v2f){2.0f, 2.0f}, t0);
    if (d2.x <= tha && ca < CAP) { lda[ca] = d2.x; lja[ca] = j0 + jj; ++ca; }
    if (d2.y <= thb && cb < CAP) { ldb[cb] = d2.y; ljb[cb] = j0 + jj; ++cb; }
  }
  counts[(b * N + row0) * NSEG + seg] = ca;
  counts[(b * N + row1) * NSEG + seg] = cb;
}

// Merge: per row, select 20 lexicographically-smallest (dist, j) from <=96
// candidates via monotone uint64 keys.
__global__ __launch_bounds__(64) void knn_merge(
    const float* __restrict__ listd, const int* __restrict__ listj,
    const int* __restrict__ counts, int* __restrict__ idxout) {
  __shared__ unsigned long long keys[64][SLOTS + 1];  // 49,664 B
  const int r0 = blockIdx.x * 64;
  const int t = threadIdx.x;
  for (int i = t; i < 64 * SLOTS; i += 64) {
    const int rr = i / SLOTS;
    const int sl = i % SLOTS;
    const int seg = sl / CAP;
    const int e = sl % CAP;
    const int row = r0 + rr;
    unsigned long long key = 0xFFFFFFFE00000000ULL | (unsigned)row;  // fallback: self
    if (e < counts[row * NSEG + seg]) {
      const float d = listd[(size_t)row * SLOTS + sl];
      unsigned ub = __float_as_uint(d);
      ub ^= (ub & 0x80000000u) ? 0xFFFFFFFFu : 0x80000000u;
      key = ((unsigned long long)ub << 32) | (unsigned)listj[(size_t)row * SLOTS + sl];
    }
    keys[rr][sl] = key;
  }
  __syncthreads();
  int* outp = idxout + (size_t)(r0 + t) * KNN;
  for (int sel = 0; sel < KNN; ++sel) {
    unsigned long long best = ~0ULL;
    int bs = 0;
#pragma unroll 8
    for (int sl = 0; sl < SLOTS; ++sl) {
      const unsigned long long k2 = keys[t][sl];
      if (k2 < best) { best = k2; bs = sl; }
    }
    keys[t][bs] = ~0ULL;
    outp[sel] = (int)(best & 0xFFFFFFFFu);
  }
}

// ---------------------------------------------------------------------------
// EdgeConv, BIT-EXACT serial semantics per (o, n, k):
//   y = sum_c W1[o,c]*x_i[c]  (prefix P)  then  += W2[o,c]*(x_j[c]-x_i[c]).
// ---------------------------------------------------------------------------

// Layer 1 (cin=3): wave per point, lane = output o.
__global__ __launch_bounds__(256) void ec_layer1(
    const float* __restrict__ pts, const int* __restrict__ idx,
    const float* __restrict__ w, const float* __restrict__ s,
    const float* __restrict__ bi, float* __restrict__ cat) {
  const int b = blockIdx.y;
  const int n = blockIdx.x * 4 + (threadIdx.x >> 6);
  const int o = threadIdx.x & 63;
  const float* p = pts + (size_t)b * 3 * N;
  const float xix = p[n], xiy = p[N + n], xiz = p[2 * N + n];
  const float* wr = w + o * 6;
  const float w0 = wr[0], w1 = wr[1], w2 = wr[2], w3 = wr[3], w4 = wr[4], w5 = wr[5];
  float P = mulrn(w0, xix);
  P = addrn(P, mulrn(w1, xiy));
  P = addrn(P, mulrn(w2, xiz));
  const float so = s[o], bo = bi[o];
  const int* ip = idx + ((size_t)b * N + n) * KNN;
  float m = 0.0f;
#pragma unroll 4
  for (int k = 0; k < KNN; ++k) {
    int j = ip[k];
    if ((unsigned)j >= (unsigned)N) j = n;
    const float ex = subrn(p[j], xix);
    const float ey = subrn(p[N + j], xiy);
    const float ez = subrn(p[2 * N + j], xiz);
    float acc = addrn(P, mulrn(w3, ex));
    acc = addrn(acc, mulrn(w4, ey));
    acc = addrn(acc, mulrn(w5, ez));
    m = fmaxf(m, addrn(mulrn(so, acc), bo));
  }
  cat[((size_t)b * N + n) * 320 + o] = m;
}

// 64-in EdgeConv as edge-GEMM: 8 points x 20 slots = 160 edges (no dups),
// OH output halves (1 -> 64 outs; 2 -> fused 128 outs, e staged ONCE).
// Edge frags: i=0,1 quads (edge=64i+4g+e) + i=2 pairs (edge=128+2g+e).
// gmax epilogue at pair granularity: row = edge>>1 (80 rows), point p owns
// rows 10p..10p+9.
template <int OH>
__global__ __launch_bounds__(256) void ec_edge(
    const float* __restrict__ cat, int inoff, const int* __restrict__ idx,
    const float* __restrict__ w, const float* __restrict__ s,
    const float* __restrict__ bi, float* __restrict__ catout, int outoff) {
  constexpr int EST = 164;         // e-chunk row stride
  constexpr int RS = 68;           // gmax row stride
  constexpr int PS = 64 * OH + 4;  // Pt row stride
  constexpr int WS = 64 * OH + 4;  // Wl2 row stride
  __shared__ float U[80 * RS];     // 21.76 KB multi-purpose (W1 / e-chunk / gmax)
  __shared__ float xis[8][64];     // 2 KB
  __shared__ float Pt[8 * PS];
  __shared__ float Wl2[16 * WS];
  __shared__ int jl[160];
  const int t = threadIdx.x;
  const int b = blockIdx.y;
  const int n0 = blockIdx.x * 8;
  const size_t bN = (size_t)b * N;

  // stage xis + jl
#pragma unroll
  for (int q = 0; q < 2; ++q) {
    const int p = (t >> 6) + 4 * q;
    const int c = t & 63;
    xis[p][c] = cat[(bN + n0 + p) * 320 + inoff + c];
  }
  if (t < 160) {
    const int p = t / 20;
    const int k = t % 20;
    int j = idx[(bN + n0 + p) * KNN + k];
    if ((unsigned)j >= (unsigned)N) j = n0 + p;  // firewall
    jl[t] = j;
  }
  __syncthreads();

  // prefix P per output-half (W1 staged through U, stride 66 -> float2 reads)
#pragma unroll
  for (int ho = 0; ho < OH; ++ho) {
#pragma unroll
    for (int q = 0; q < 16; ++q) {
      const int l = t + 256 * q;
      U[(l >> 6) * 66 + (l & 63)] = w[(ho * 64 + (l >> 6)) * 128 + (l & 63)];
    }
    __syncthreads();
    {
      const int o = t & 63;
      const int p0 = t >> 6;
      const float2* wq = (const float2*)&U[o * 66];
      const float2* x0 = (const float2*)&xis[p0][0];
      const float2* x1 = (const float2*)&xis[p0 + 4][0];
      float2 wv = wq[0];
      float2 a0 = x0[0];
      float2 a1 = x1[0];
      float P0 = mulrn(wv.x, a0.x);
      float P1 = mulrn(wv.x, a1.x);
      P0 = addrn(P0, mulrn(wv.y, a0.y));
      P1 = addrn(P1, mulrn(wv.y, a1.y));
#pragma unroll
      for (int c2 = 1; c2 < 32; ++c2) {
        wv = wq[c2];
        a0 = x0[c2];
        a1 = x1[c2];
        P0 = addrn(P0, mulrn(wv.x, a0.x));
        P1 = addrn(P1, mulrn(wv.x, a1.x));
        P0 = addrn(P0, mulrn(wv.y, a0.y));
        P1 = addrn(P1, mulrn(wv.y, a1.y));
      }
      Pt[p0 * PS + ho * 64 + o] = P0;
      Pt[(p0 + 4) * PS + ho * 64 + o] = P1;
    }
    __syncthreads();
  }

  const int g = t & 15;  // edge-frag lane
  const int h = t >> 4;  // output-frag lane: outputs 64*ho + 4h + u
  v2f a4[2][4][2 * OH];  // quad frags (i=0,1)
  v2f a2p[2][2 * OH];    // pair frag (i=2)
#pragma unroll
  for (int i = 0; i < 2; ++i) {
    const int p = (64 * i + 4 * g) / 20;
#pragma unroll
    for (int ho = 0; ho < OH; ++ho) {
      const float4 Pv = *(const float4*)&Pt[p * PS + ho * 64 + 4 * h];
#pragma unroll
      for (int e = 0; e < 4; ++e) {
        a4[i][e][2 * ho] = (v2f){Pv.x, Pv.y};
        a4[i][e][2 * ho + 1] = (v2f){Pv.z, Pv.w};
      }
    }
  }
  {
    const int p = (128 + 2 * g) / 20;
#pragma unroll
    for (int ho = 0; ho < OH; ++ho) {
      const float4 Pv = *(const float4*)&Pt[p * PS + ho * 64 + 4 * h];
#pragma unroll
      for (int e = 0; e < 2; ++e) {
        a2p[e][2 * ho] = (v2f){Pv.x, Pv.y};
        a2p[e][2 * ho + 1] = (v2f){Pv.z, Pv.w};
      }
    }
  }

  // K chunks: stage Wl2 + e-chunk, then pure MAC phase (ascending c)
  for (int kc = 0; kc < 64; kc += 16) {
#pragma unroll
    for (int ho = 0; ho < OH; ++ho) {
      const int o = t >> 2;
      const int cq = t & 3;
      const float4 wv = *(const float4*)&w[(ho * 64 + o) * 128 + 64 + kc + 4 * cq];
      Wl2[(4 * cq + 0) * WS + ho * 64 + o] = wv.x;
      Wl2[(4 * cq + 1) * WS + ho * 64 + o] = wv.y;
      Wl2[(4 * cq + 2) * WS + ho * 64 + o] = wv.z;
      Wl2[(4 * cq + 3) * WS + ho * 64 + o] = wv.w;
    }
#pragma unroll
    for (int q = 0; q < 3; ++q) {
      const int sl = 64 * q + (t >> 2);
      const int cq = t & 3;
      if (sl < 160) {
        const int p = sl / 20;
        const int j = jl[sl];
        const float4 xj = *(const float4*)&cat[(bN + j) * 320 + inoff + kc + 4 * cq];
        const float4 xv = *(const float4*)&xis[p][kc + 4 * cq];
        U[(4 * cq + 0) * EST + sl] = subrn(xj.x, xv.x);
        U[(4 * cq + 1) * EST + sl] = subrn(xj.y, xv.y);
        U[(4 * cq + 2) * EST + sl] = subrn(xj.z, xv.z);
        U[(4 * cq + 3) * EST + sl] = subrn(xj.w, xv.w);
      }
    }
    __syncthreads();
#pragma unroll
    for (int k = 0; k < 16; ++k) {
      const float4 ef0 = *(const float4*)&U[k * EST + 4 * g];
      const float4 ef1 = *(const float4*)&U[k * EST + 64 + 4 * g];
      const v2f ef2 = *(const v2f*)&U[k * EST + 128 + 2 * g];
      const float e0[4] = {ef0.x, ef0.y, ef0.z, ef0.w};
      const float e1[4] = {ef1.x, ef1.y, ef1.z, ef1.w};
      const float e2[2] = {ef2.x, ef2.y};
#pragma unroll
      for (int ho = 0; ho < OH; ++ho) {
        const float4 wf = *(const float4*)&Wl2[k * WS + ho * 64 + 4 * h];
        const v2f w01 = (v2f){wf.x, wf.y};
        const v2f w23 = (v2f){wf.z, wf.w};
#pragma unroll
        for (int e = 0; e < 4; ++e) {
          const v2f x0 = (v2f){e0[e], e0[e]};
          a4[0][e][2 * ho] = addrn2(a4[0][e][2 * ho], mulrn2(w01, x0));
          a4[0][e][2 * ho + 1] = addrn2(a4[0][e][2 * ho + 1], mulrn2(w23, x0));
          const v2f x1 = (v2f){e1[e], e1[e]};
          a4[1][e][2 * ho] = addrn2(a4[1][e][2 * ho], mulrn2(w01, x1));
          a4[1][e][2 * ho + 1] = addrn2(a4[1][e][2 * ho + 1], mulrn2(w23, x1));
        }
#pragma unroll
        for (int e = 0; e < 2; ++e) {
          const v2f x2 = (v2f){e2[e], e2[e]};
          a2p[e][2 * ho] = addrn2(a2p[e][2 * ho], mulrn2(w01, x2));
          a2p[e][2 * ho + 1] = addrn2(a2p[e][2 * ho + 1], mulrn2(w23, x2));
        }
      }
    }
    __syncthreads();  // U readers done before restage / gmax
  }

  // epilogue per half: relu(s*acc+b) per edge, pair-max rows, point reduce
#pragma unroll
  for (int ho = 0; ho < OH; ++ho) {
    const float4 sv = *(const float4*)&s[ho * 64 + 4 * h];
    const float4 bv = *(const float4*)&bi[ho * 64 + 4 * h];
    const float sc[4] = {sv.x, sv.y, sv.z, sv.w};
    const float bc[4] = {bv.x, bv.y, bv.z, bv.w};
#pragma unroll
    for (int i = 0; i < 2; ++i) {
#pragma unroll
      for (int ep = 0; ep < 2; ++ep) {
        const int row = 32 * i + 2 * g + ep;
        float gm[4] = {0.f, 0.f, 0.f, 0.f};
#pragma unroll
        for (int ee = 0; ee < 2; ++ee) {
          const int e = 2 * ep + ee;
#pragma unroll
          for (int u = 0; u < 4; ++u) {
            const v2f a = a4[i][e][2 * ho + (u >> 1)];
            const float av = (u & 1) ? a.y : a.x;
            gm[u] = fmaxf(gm[u], fmaxf(addrn(mulrn(sc[u], av), bc[u]), 0.f));
          }
        }
        *(float4*)&U[row * RS + 4 * h] = make_float4(gm[0], gm[1], gm[2], gm[3]);
      }
    }
    {
      const int row = 64 + g;
      float gm[4] = {0.f, 0.f, 0.f, 0.f};
#pragma unroll
      for (int e = 0; e < 2; ++e) {
#pragma unroll
        for (int u = 0; u < 4; ++u) {
          const v2f a = a2p[e][2 * ho + (u >> 1)];
          const float av = (u & 1) ? a.y : a.x;
          gm[u] = fmaxf(gm[u], fmaxf(addrn(mulrn(sc[u], av), bc[u]), 0.f));
        }
      }
      *(float4*)&U[row * RS + 4 * h] = make_float4(gm[0], gm[1], gm[2], gm[3]);
    }
    __syncthreads();
#pragma unroll
    for (int q = 0; q < 2; ++q) {
      const int o = t & 63;
      const int p = (t >> 6) + 4 * q;
      const float* ur = &U[(10 * p) * RS + o];
      float m = ur[0];
#pragma unroll
      for (int r = 1; r < 10; ++r) m = fmaxf(m, ur[r * RS]);
      catout[(bN + n0 + p) * 320 + outoff + ho * 64 + o] = m;
    }
    if (ho + 1 < OH) __syncthreads();  // pass 2 rewrites U
  }
}

// ---------------------------------------------------------------------------
// Local layer: loc[o][n] = relu(s*<W[o,:],cat[n,:]>+b), serial ascending c,
// output-pair pk-packed, b128 LDS fragments. XOR-2 column swizzle on staging
// stores (perm in {0,2}: 2-way banks = free; intra-v2f-pair order preserved;
// unswizzle is compile-time renaming in the unrolled k-loop).
// ---------------------------------------------------------------------------
__global__ __launch_bounds__(256) void local_gemm(
    const float* __restrict__ cat, const float* __restrict__ w,
    const float* __restrict__ s, const float* __restrict__ bi,
    float* __restrict__ pval, int* __restrict__ pidx) {
  constexpr int KC = 32;
  constexpr int XS = 132;
  __shared__ float smem[KC * XS * 2];  // 33,792 B
  float* xs = smem;
  float* wsd = smem + KC * XS;
  const int t = threadIdx.x;
  const int q0 = blockIdx.x * 128;
  const int ptile = blockIdx.y;
  const size_t pt0 = (size_t)ptile * 128;
  const int g = t & 15;
  const int h = t >> 4;
  v2f acc2[2][2][4][2];
#pragma unroll
  for (int ep = 0; ep < 2; ++ep)
#pragma unroll
    for (int fp = 0; fp < 2; ++fp)
#pragma unroll
      for (int pi = 0; pi < 4; ++pi)
#pragma unroll
        for (int u = 0; u < 2; ++u) acc2[ep][fp][pi][u] = (v2f){0.f, 0.f};

  const int lk = t & 31;
  const int lp = t >> 5;
  const int px = ((lk >> 3) & 1) << 1;  // store swizzle: 0 or 2
  const float* catp = cat + pt0 * 320 + lk;
  const float* wp = w + (size_t)q0 * 320 + lk;
  float rx[16], rw[16];
#pragma unroll
  for (int i = 0; i < 16; ++i) rx[i] = catp[(size_t)(lp + 8 * i) * 320];
#pragma unroll
  for (int i = 0; i < 16; ++i) rw[i] = wp[(size_t)(lp + 8 * i) * 320];

  for (int kc = 0; kc < 320; kc += KC) {
#pragma unroll
    for (int i = 0; i < 16; ++i) xs[lk * XS + ((lp + 8 * i) ^ px)] = rx[i];
#pragma unroll
    for (int i = 0; i < 16; ++i) wsd[lk * XS + ((lp + 8 * i) ^ px)] = rw[i];
    __syncthreads();
    if (kc + KC < 320) {  // prefetch next chunk into registers
      const int ko = kc + KC;
#pragma unroll
      for (int i = 0; i < 16; ++i) rx[i] = catp[(size_t)(lp + 8 * i) * 320 + ko];
#pragma unroll
      for (int i = 0; i < 16; ++i) rw[i] = wp[(size_t)(lp + 8 * i) * 320 + ko];
    }
#pragma unroll
    for (int k = 0; k < KC; ++k) {
      const int pm = (k >> 3) & 1;  // compile-time under unroll
      float4 wfr[2];
#pragma unroll
      for (int fp = 0; fp < 2; ++fp)
        wfr[fp] = *(const float4*)&wsd[k * XS + 64 * fp + 4 * h];
#pragma unroll
      for (int ep = 0; ep < 2; ++ep) {
        const float4 xr = *(const float4*)&xs[k * XS + 64 * ep + 4 * g];
        float xv[4];
        if (pm) { xv[0] = xr.z; xv[1] = xr.w; xv[2] = xr.x; xv[3] = xr.y; }
        else    { xv[0] = xr.x; xv[1] = xr.y; xv[2] = xr.z; xv[3] = xr.w; }
#pragma unroll
        for (int fp = 0; fp < 2; ++fp) {
          const float4 wf = wfr[fp];
          const v2f w0 = pm ? (v2f){wf.z, wf.w} : (v2f){wf.x, wf.y};
          const v2f w1 = pm ? (v2f){wf.x, wf.y} : (v2f){wf.z, wf.w};
#pragma unroll
          for (int pi = 0; pi < 4; ++pi) {
            const v2f xx = (v2f){xv[pi], xv[pi]};
            acc2[ep][fp][pi][0] = addrn2(acc2[ep][fp][pi][0], mulrn2(w0, xx));
            acc2[ep][fp][pi][1] = addrn2(acc2[ep][fp][pi][1], mulrn2(w1, xx));
          }
        }
      }
    }
    __syncthreads();
  }
  // epilogue: relu(s*acc+b), per-thread argmax over 8 points ascending
  const int bb = ptile >> 5;
  const int blk = ptile & 31;
  float mv[8];
  int mi[8];
#pragma unroll
  for (int fp = 0; fp < 2; ++fp)
#pragma unroll
    for (int c = 0; c < 4; ++c) {
      const int f = fp * 4 + c;
      const int cl = 64 * fp + 4 * h + c;
      const float sc = s[q0 + cl];
      const float bc = bi[q0 + cl];
      mv[f] = -1.f;
      mi[f] = 0;
#pragma unroll
      for (int ep = 0; ep < 2; ++ep)
#pragma unroll
        for (int pi = 0; pi < 4; ++pi) {
          const v2f a2 = acc2[ep][fp][pi][c >> 1];
          const float a = (c & 1) ? a2.y : a2.x;
          const float v = fmaxf(addrn(mulrn(sc, a), bc), 0.f);
          if (v > mv[f]) { mv[f] = v; mi[f] = 64 * ep + 4 * g + pi; }
        }
    }
  __syncthreads();
  float* smv = smem;
  int* smi = (int*)(smem + 16 * 132);
#pragma unroll
  for (int fp = 0; fp < 2; ++fp)
#pragma unroll
    for (int c = 0; c < 4; ++c) {
      const int cl = 64 * fp + 4 * h + c;
      smv[g * 132 + cl] = mv[fp * 4 + c];
      smi[g * 132 + cl] = mi[fp * 4 + c];
    }
  __syncthreads();
  if (t < 128) {
    float best = smv[t];
    int bidx = smi[t];
    for (int gg = 1; gg < 16; ++gg) {
      const float v = smv[gg * 132 + t];
      const int vi = smi[gg * 132 + t];
      // candidates g-interleaved: ties resolve to SMALLEST point idx
      if (v > best || (v == best && vi < bidx)) { best = v; bidx = vi; }
    }
    const int n_l = blk * 128 + bidx;
    const size_t po = ((size_t)bb * 1024 + q0 + t) * 32 + blk;
    pval[po] = best;
    pidx[po] = n_l;
  }
}

__global__ __launch_bounds__(256) void final_reduce(
    const float* __restrict__ pval, const int* __restrict__ pidx,
    float* __restrict__ glob, float* __restrict__ oidx) {
  const int o = blockIdx.x * 256 + threadIdx.x;  // 8192 = B*1024
  const float* pv = pval + (size_t)o * 32;
  const int* pi = pidx + (size_t)o * 32;
  float best = pv[0];
  int bi = pi[0];
  for (int k = 1; k < 32; ++k) {
    const float v = pv[k];
    // tiles are ascending disjoint point ranges: strict > = first occurrence
    if (v > best) { best = v; bi = pi[k]; }
  }
  glob[o] = best;
  oidx[o] = (float)bi;
}

template <int KIN, int OUTS>
__global__ __launch_bounds__(256) void dense_wave(
    const float* __restrict__ in, const float* __restrict__ w,
    const float* __restrict__ s, const float* __restrict__ bi,
    float* __restrict__ out) {
  const int wid = (blockIdx.x * 256 + threadIdx.x) >> 6;
  const int lane = threadIdx.x & 63;
  const int b = wid / OUTS;
  const int o = wid % OUTS;
  const float* ip = in + (size_t)b * KIN;
  const float* wr = w + (size_t)o * KIN;
  float acc = 0.f;
  for (int k = lane; k < KIN; k += 64) acc = fmaf(wr[k], ip[k], acc);
#pragma unroll
  for (int off = 32; off; off >>= 1) acc += __shfl_down(acc, off);
  if (lane == 0) out[(size_t)b * OUTS + o] = fmaxf(fmaf(s[o], acc, bi[o]), 0.f);
}

extern "C" void kernel_launch(void* const* d_in, const int* in_sizes, int n_in,
                              void* d_out, int out_size, void* d_ws, size_t ws_size,
                              hipStream_t stream) {
  (void)in_sizes; (void)n_in; (void)out_size; (void)ws_size;
  const float* pts = (const float*)d_in[0];
  const float* ec_w[4] = {(const float*)d_in[1], (const float*)d_in[4],
                          (const float*)d_in[7], (const float*)d_in[10]};
  const float* ec_s[4] = {(const float*)d_in[2], (const float*)d_in[5],
                          (const float*)d_in[8], (const float*)d_in[11]};
  const float* ec_b[4] = {(const float*)d_in[3], (const float*)d_in[6],
                          (const float*)d_in[9], (const float*)d_in[12]};
  const float* local_w = (const float*)d_in[13];
  const float* local_s = (const float*)d_in[14];
  const float* local_b = (const float*)d_in[15];
  const float* g_w0 = (const float*)d_in[16];
  const float* g_s0 = (const float*)d_in[17];
  const float* g_b0 = (const float*)d_in[18];
  const float* g_w1 = (const float*)d_in[19];
  const float* g_s1 = (const float*)d_in[20];
  const float* g_b1 = (const float*)d_in[21];

  char* ws = (char*)d_ws;
  int* idxbuf = (int*)(ws + OFF_IDX);
  float* cat = (float*)(ws + OFF_CAT);
  float* pv = (float*)(ws + OFF_PV);
  int* pi = (int*)(ws + OFF_PI);
  float* glob = (float*)(ws + OFF_GLOB);
  float* hbuf = (float*)(ws + OFF_H);
  float* listd = (float*)(ws + OFF_LD);
  int* listj = (int*)(ws + OFF_LJ);
  int* counts = (int*)(ws + OFF_CNT);
  float* outv = (float*)d_out;   // [8][256]  fp32
  float* oidx = outv + 2048;     // [8][1024] fp32 (indices as floats)

  knn_scan<<<dim3(32, 8), 256, 0, stream>>>(pts, listd, listj, counts);
  knn_merge<<<dim3(512), 64, 0, stream>>>(listd, listj, counts, idxbuf);

  // layer 1 (3 -> 64)
  ec_layer1<<<dim3(1024, 8), 256, 0, stream>>>(pts, idxbuf, ec_w[0], ec_s[0], ec_b[0], cat);
  // layer 2 (64 -> 64)
  ec_edge<1><<<dim3(512, 8), 256, 0, stream>>>(cat, 0, idxbuf, ec_w[1], ec_s[1], ec_b[1], cat, 64);
  // layer 3 (64 -> 64)
  ec_edge<1><<<dim3(512, 8), 256, 0, stream>>>(cat, 64, idxbuf, ec_w[2], ec_s[2], ec_b[2], cat, 128);
  // layer 4 (64 -> 128), fused both output halves, e staged once
  ec_edge<2><<<dim3(512, 8), 256, 0, stream>>>(cat, 128, idxbuf, ec_w[3], ec_s[3], ec_b[3], cat, 192);

  local_gemm<<<dim3(8, 256), 256, 0, stream>>>(cat, local_w, local_s, local_b, pv, pi);
  final_reduce<<<dim3(32), 256, 0, stream>>>(pv, pi, glob, oidx);
  dense_wave<1024, 512><<<dim3(1024), 256, 0, stream>>>(glob, g_w0, g_s0, g_b0, hbuf);
  dense_wave<512, 256><<<dim3(512), 256, 0, stream>>>(hbuf, g_w1, g_s1, g_b1, outv);
}